// Round 6
// baseline (1659.232 us; speedup 1.0000x reference)
//
#include <hip/hip_runtime.h>
#include <hip/hip_bf16.h>

typedef __bf16 bf16x8 __attribute__((ext_vector_type(8)));
typedef float  f32x4  __attribute__((ext_vector_type(4)));
typedef unsigned short u16x8 __attribute__((ext_vector_type(8)));
typedef unsigned short u16x4 __attribute__((ext_vector_type(4)));

#define CH    256
#define IMG   112
#define WSZ   7
#define TOK   49
#define NWIN  4096

// ---- LDS arena (77,824 B total -> 2 blocks/CU) ----
// R1 [0, 42496): n1F frags (32K)  ->  win2b bf16 (25,872) + HM quarter (16K @25888)
// R2 [42496, 75264): sXb bf16 (25,872) -> head bufs (Q 8K|K 8K|V 8K|P 7K; O over Q) -> n2F (32K)
// misc [75264, 77824): sM 256 | sR 256 | sPart 2048
#define OFF_R1   0
#define W2B_ST   264
#define OFF_HMQ  25888
#define OFF_R2   42496
#define SXB_ST   264
#define OFF_QH   (OFF_R2 + 0)
#define OFF_KH   (OFF_R2 + 8192)
#define OFF_VH   (OFF_R2 + 16384)
#define OFF_PH   (OFF_R2 + 24576)
#define OFF_OH   (OFF_R2 + 0)
#define OFF_N2F  OFF_R2
#define OFF_MISC 75264
#define SMEM_SZ  77824

// ---- d_ws layout: bf16 B-fragment blocks, 1KB each ----
#define WS_PROJ_BLK 384
#define WS_W1_BLK   512
#define WS_W2_BLK   768

__device__ __forceinline__ unsigned short f2bf(float f) {
    __bf16 h = (__bf16)f;
    return __builtin_bit_cast(unsigned short, h);
}
__device__ __forceinline__ float bfu(unsigned short u) {
    return __uint_as_float(((unsigned)u) << 16);
}
__device__ __forceinline__ f32x4 mfma16(bf16x8 a, bf16x8 b, f32x4 c) {
    return __builtin_amdgcn_mfma_f32_16x16x32_bf16(a, b, c, 0, 0, 0);
}

// frag-block element byte offsets
__device__ __forceinline__ int frOff2(int base, int t, int c) {   // 64-col arena
    return base + (((t >> 4) * 2 + (c >> 5)) << 10)
                + (((((c >> 3) & 3) << 4) | (t & 15)) << 4) + ((c & 7) << 1);
}
__device__ __forceinline__ int frOffT2(int base, int d, int s) {  // V^T 64x64 arena
    return base + (((d >> 4) * 2 + (s >> 5)) << 10)
                + (((((s >> 3) & 3) << 4) | (d & 15)) << 4) + ((s & 7) << 1);
}
__device__ __forceinline__ int frOffH(int t, int c) {             // 128-col HM quarter
    return OFF_HMQ + (((t >> 4) * 4 + (c >> 5)) << 10)
                + (((((c >> 3) & 3) << 4) | (t & 15)) << 4) + ((c & 7) << 1);
}

// ---------------- prepack: fp32 weights -> bf16 B-fragment blocks in d_ws ----------------
extern "C" __global__ __launch_bounds__(64)
void prepack(const float* __restrict__ qkv_w, const float* __restrict__ proj_w,
             const float* __restrict__ w1, const float* __restrict__ w2,
             char* __restrict__ ws)
{
    const int blk = blockIdx.x, l = threadIdx.x;
    const float* W; int nt, kt, ncols;
    if (blk < WS_PROJ_BLK)      { W = qkv_w;  int i = blk;               nt = i >> 3; kt = i & 7;  ncols = 768; }
    else if (blk < WS_W1_BLK)   { W = proj_w; int i = blk - WS_PROJ_BLK; nt = i >> 3; kt = i & 7;  ncols = 256; }
    else if (blk < WS_W2_BLK)   { W = w1;     int i = blk - WS_W1_BLK;   nt = i >> 3; kt = i & 7;  ncols = 512; }
    else                        { W = w2;     int i = blk - WS_W2_BLK;   nt = i >> 4; kt = i & 15; ncols = 256; }
    const int n  = nt * 16 + (l & 15);
    const int k0 = kt * 32 + (l >> 4) * 8;
    u16x8 o;
    #pragma unroll
    for (int j = 0; j < 8; ++j) o[j] = f2bf(W[(size_t)(k0 + j) * ncols + n]);
    *(u16x8*)(ws + (size_t)blk * 1024 + l * 16) = o;
}

// ---------------- main fused block: 8 waves, 2 blocks/CU ----------------
extern "C" __global__ __launch_bounds__(512, 2)
void swin_block(const float* __restrict__ x,
                const float* __restrict__ ln1_g, const float* __restrict__ ln1_b,
                const float* __restrict__ qkv_b,
                const float* __restrict__ proj_b,
                const float* __restrict__ ln2_g, const float* __restrict__ ln2_b,
                const float* __restrict__ b1, const float* __restrict__ b2,
                const char* __restrict__ ws,
                float* __restrict__ y)
{
    __shared__ __align__(16) char smem[SMEM_SZ];
    float*  sM    = (float*)(smem + OFF_MISC);
    float*  sR    = (float*)(smem + OFF_MISC + 256);
    float2* sPart = (float2*)(smem + OFF_MISC + 512);

    const int tid  = threadIdx.x;
    const int wid  = tid >> 6;       // 0..7
    const int lane = tid & 63;
    const int sub  = lane >> 4;
    const int l15  = lane & 15;
    const int mg   = wid >> 2;       // m-half 0..1
    const int ng4  = wid & 3;        // n-group 0..3
    const int ah   = wid & 3;        // attn row-quarter
    const int chh  = wid >> 2;       // attn col-half

    const int n  = blockIdx.x;
    const int b  = n >> 8;
    const int wh = (n >> 4) & 15;
    const int ww = n & 15;
    const int row0 = wh * WSZ, col0 = ww * WSZ;
    const size_t xbase = (size_t)b * CH * IMG * IMG;

    const f32x4 z4 = {0.f, 0.f, 0.f, 0.f};

    // ---- P0: stage x -> sXb (bf16 [t][c], stride 264) ----
    for (int e = tid; e < TOK * CH; e += 512) {
        int j = e % 7; int rem = e / 7; int i = rem % 7; int c = rem / 7;
        int t = i * 7 + j;
        *(unsigned short*)(smem + OFF_R2 + ((t * SXB_ST + c) << 1)) =
            f2bf(x[xbase + ((size_t)c * IMG + row0 + i) * IMG + col0 + j]);
    }
    __syncthreads();

    // ---- P1: LN1 stats (from bf16 x) ----
    for (int t = wid; t < TOK; t += 8) {
        u16x4 v4 = *(const u16x4*)(smem + OFF_R2 + ((t * SXB_ST + lane * 4) << 1));
        float a0 = bfu(v4[0]), a1 = bfu(v4[1]), a2 = bfu(v4[2]), a3 = bfu(v4[3]);
        float s1 = a0 + a1 + a2 + a3;
        float s2 = a0 * a0 + a1 * a1 + a2 * a2 + a3 * a3;
        #pragma unroll
        for (int off = 32; off > 0; off >>= 1) {
            s1 += __shfl_xor(s1, off);
            s2 += __shfl_xor(s2, off);
        }
        if (lane == 0) {
            float m = s1 * (1.f / 256.f);
            float var = s2 * (1.f / 256.f) - m * m;
            sM[t] = m; sR[t] = rsqrtf(var + 1e-5f);
        }
    }
    __syncthreads();

    // ---- P2: LN1 normalize -> n1F frags (R1); zero pad rows ----
    for (int e = tid; e < 2048; e += 512) {
        int t = e & 63, cb = e >> 6;
        char* dst = smem + OFF_R1 + (((t >> 4) * 8 + (cb >> 2)) << 10)
                  + (((((cb & 3) << 4) | (t & 15))) << 4);
        if (t < TOK) {
            u16x8 xv = *(const u16x8*)(smem + OFF_R2 + ((t * SXB_ST + cb * 8) << 1));
            int c = cb * 8;
            float4 ga = *(const float4*)(ln1_g + c), gb = *(const float4*)(ln1_g + c + 4);
            float4 ba = *(const float4*)(ln1_b + c), bb = *(const float4*)(ln1_b + c + 4);
            float m = sM[t], rs = sR[t];
            u16x8 o;
            o[0] = f2bf((bfu(xv[0]) - m) * rs * ga.x + ba.x);
            o[1] = f2bf((bfu(xv[1]) - m) * rs * ga.y + ba.y);
            o[2] = f2bf((bfu(xv[2]) - m) * rs * ga.z + ba.z);
            o[3] = f2bf((bfu(xv[3]) - m) * rs * ga.w + ba.w);
            o[4] = f2bf((bfu(xv[4]) - m) * rs * gb.x + bb.x);
            o[5] = f2bf((bfu(xv[5]) - m) * rs * gb.y + bb.y);
            o[6] = f2bf((bfu(xv[6]) - m) * rs * gb.z + bb.z);
            o[7] = f2bf((bfu(xv[7]) - m) * rs * gb.w + bb.w);
            *(u16x8*)dst = o;
        } else {
            u16x8 z = {0, 0, 0, 0, 0, 0, 0, 0};
            *(u16x8*)dst = z;
        }
    }
    __syncthreads();

    // ---- P3/P4: head loop: QKV_h -> attn_h -> proj partial (acc in regs) ----
    f32x4 accp[4][2];
    #pragma unroll
    for (int j = 0; j < 4; ++j) { accp[j][0] = z4; accp[j][1] = z4; }

    for (int h = 0; h < 4; ++h) {
        // -- QKV GEMM for head h: wave (mg,ng4) does 1 ntile each of Q,K,V --
        #pragma unroll
        for (int mtx = 0; mtx < 3; ++mtx) {
            const int ntg = mtx * 16 + h * 4 + ng4;
            bf16x8 bF[8];
            #pragma unroll
            for (int kt = 0; kt < 8; ++kt)
                bF[kt] = *(const bf16x8*)(ws + ((size_t)(ntg * 8 + kt) << 10) + lane * 16);
            f32x4 acc[2] = {z4, z4};
            #pragma unroll
            for (int kt = 0; kt < 8; ++kt) {
                bf16x8 a0 = *(const bf16x8*)(smem + OFF_R1 + (((mg * 2 + 0) * 8 + kt) << 10) + lane * 16);
                bf16x8 a1 = *(const bf16x8*)(smem + OFF_R1 + (((mg * 2 + 1) * 8 + kt) << 10) + lane * 16);
                acc[0] = mfma16(a0, bF[kt], acc[0]);
                acc[1] = mfma16(a1, bF[kt], acc[1]);
            }
            const int cl = ng4 * 16 + l15;                 // head-local col 0..63
            const float bias = qkv_b[mtx * 256 + h * 64 + cl];
            if (mtx == 0) {
                #pragma unroll
                for (int m = 0; m < 2; ++m)
                    #pragma unroll
                    for (int r = 0; r < 4; ++r) {
                        int t = (mg * 2 + m) * 16 + sub * 4 + r;
                        *(unsigned short*)(smem + frOff2(OFF_QH, t, cl)) = f2bf((acc[m][r] + bias) * 0.125f);
                    }
            } else if (mtx == 1) {
                #pragma unroll
                for (int m = 0; m < 2; ++m)
                    #pragma unroll
                    for (int r = 0; r < 4; ++r) {
                        int t = (mg * 2 + m) * 16 + sub * 4 + r;
                        *(unsigned short*)(smem + frOff2(OFF_KH, t, cl)) = f2bf(acc[m][r] + bias);
                    }
            } else {
                #pragma unroll
                for (int m = 0; m < 2; ++m)
                    #pragma unroll
                    for (int r = 0; r < 4; ++r) {
                        int t = (mg * 2 + m) * 16 + sub * 4 + r;
                        *(unsigned short*)(smem + frOffT2(OFF_VH, cl, t)) = f2bf(acc[m][r] + bias);
                    }
            }
        }
        __syncthreads();   // A: Q/K/V ready

        // -- QK^T: wave (ah, chh): rows ah*16+:16, cols chh*32+:32 --
        f32x4 sc[2] = {z4, z4};
        {
            bf16x8 qf[2], kf[2][2];
            #pragma unroll
            for (int k2 = 0; k2 < 2; ++k2)
                qf[k2] = *(const bf16x8*)(smem + OFF_QH + ((ah * 2 + k2) << 10) + lane * 16);
            #pragma unroll
            for (int nt = 0; nt < 2; ++nt)
                #pragma unroll
                for (int k2 = 0; k2 < 2; ++k2)
                    kf[nt][k2] = *(const bf16x8*)(smem + OFF_KH + (((chh * 2 + nt) * 2 + k2) << 10) + lane * 16);
            #pragma unroll
            for (int k2 = 0; k2 < 2; ++k2) {
                sc[0] = mfma16(qf[k2], kf[0][k2], sc[0]);
                sc[1] = mfma16(qf[k2], kf[1][k2], sc[1]);
            }
        }
        float mxl[4];
        #pragma unroll
        for (int r = 0; r < 4; ++r) {
            const int t = ah * 16 + sub * 4 + r;
            float v0 = sc[0][r];
            float v1 = (chh == 1 && l15 > 0) ? -1e30f : sc[1][r];   // mask s>=49
            sc[1][r] = v1;
            float mx = fmaxf(v0, v1);
            mx = fmaxf(mx, __shfl_xor(mx, 1));
            mx = fmaxf(mx, __shfl_xor(mx, 2));
            mx = fmaxf(mx, __shfl_xor(mx, 4));
            mx = fmaxf(mx, __shfl_xor(mx, 8));
            mxl[r] = mx;
            float e0 = __expf(v0 - mx), e1 = __expf(v1 - mx);
            float sm = e0 + e1;
            sm += __shfl_xor(sm, 1);
            sm += __shfl_xor(sm, 2);
            sm += __shfl_xor(sm, 4);
            sm += __shfl_xor(sm, 8);
            if (l15 == 0 && t < TOK) sPart[t * 2 + chh] = make_float2(mx, sm);
        }
        __syncthreads();   // B: partials ready

        // -- merge partials + write P (bf16, [t][s], stride 144B) --
        #pragma unroll
        for (int r = 0; r < 4; ++r) {
            const int t = ah * 16 + sub * 4 + r;
            if (t < TOK) {
                float2 p0 = sPart[t * 2 + 0], p1 = sPart[t * 2 + 1];
                float M = fmaxf(p0.x, p1.x);
                float denom = p0.y * __expf(p0.x - M) + p1.y * __expf(p1.x - M);
                float scale = __expf(mxl[r] - M) / denom;
                unsigned short* pr = (unsigned short*)(smem + OFF_PH + t * 144);
                pr[chh * 32 + l15]      = f2bf(__expf(sc[0][r] - mxl[r]) * scale);
                pr[chh * 32 + 16 + l15] = f2bf(__expf(sc[1][r] - mxl[r]) * scale);
            }
        }
        __syncthreads();   // C: P ready (Q also fully consumed)

        // -- PV: wave (ah, nh=chh): O rows ah*16+:16, cols chh*32+:32 --
        {
            bf16x8 pf[2], vf[2][2];
            int rowc = ah * 16 + l15; rowc = rowc > 48 ? 48 : rowc;
            #pragma unroll
            for (int k2 = 0; k2 < 2; ++k2)
                pf[k2] = *(const bf16x8*)(smem + OFF_PH + rowc * 144 + ((k2 * 32 + sub * 8) << 1));
            #pragma unroll
            for (int nt = 0; nt < 2; ++nt)
                #pragma unroll
                for (int k2 = 0; k2 < 2; ++k2)
                    vf[nt][k2] = *(const bf16x8*)(smem + OFF_VH + (((chh * 2 + nt) * 2 + k2) << 10) + lane * 16);
            f32x4 oc[2] = {z4, z4};
            #pragma unroll
            for (int k2 = 0; k2 < 2; ++k2) {
                oc[0] = mfma16(pf[k2], vf[0][k2], oc[0]);
                oc[1] = mfma16(pf[k2], vf[1][k2], oc[1]);
            }
            #pragma unroll
            for (int nt = 0; nt < 2; ++nt)
                #pragma unroll
                for (int r = 0; r < 4; ++r) {
                    int t = ah * 16 + sub * 4 + r;
                    int c = (chh * 2 + nt) * 16 + l15;
                    *(unsigned short*)(smem + frOff2(OFF_OH, t, c)) = f2bf(oc[nt][r]);
                }
        }
        __syncthreads();   // D: O_h ready

        // -- proj partial: wave (mg,ng4): accp[j][m] += O_h @ Wproj[h*64+:64, ng4*64+:64] --
        {
            bf16x8 aO[2][2];
            #pragma unroll
            for (int m = 0; m < 2; ++m)
                #pragma unroll
                for (int k2 = 0; k2 < 2; ++k2)
                    aO[m][k2] = *(const bf16x8*)(smem + OFF_OH + (((mg * 2 + m) * 2 + k2) << 10) + lane * 16);
            #pragma unroll
            for (int j = 0; j < 4; ++j) {
                bf16x8 b0 = *(const bf16x8*)(ws + ((size_t)(WS_PROJ_BLK + (ng4 * 4 + j) * 8 + h * 2 + 0) << 10) + lane * 16);
                bf16x8 b1 = *(const bf16x8*)(ws + ((size_t)(WS_PROJ_BLK + (ng4 * 4 + j) * 8 + h * 2 + 1) << 10) + lane * 16);
                #pragma unroll
                for (int m = 0; m < 2; ++m) {
                    accp[j][m] = mfma16(aO[m][0], b0, accp[j][m]);
                    accp[j][m] = mfma16(aO[m][1], b1, accp[j][m]);
                }
            }
        }
        __syncthreads();   // E: O_h region free for next head's Q
    }

    // ---- P6: proj epilogue: win2 = x + proj + bias -> win2b (bf16); LN2 partial stats ----
    {
        float ps1[2][4], ps2[2][4];
        #pragma unroll
        for (int m = 0; m < 2; ++m) {
            #pragma unroll
            for (int r = 0; r < 4; ++r) {
                const int t = (mg * 2 + m) * 16 + sub * 4 + r;
                ps1[m][r] = 0.f; ps2[m][r] = 0.f;
                if (t < TOK) {
                    const int i7 = t / 7, jj = t - i7 * 7;
                    float a = 0.f, bb = 0.f;
                    #pragma unroll
                    for (int j = 0; j < 4; ++j) {
                        const int c = (ng4 * 4 + j) * 16 + l15;
                        float xi = x[xbase + ((size_t)c * IMG + row0 + i7) * IMG + col0 + jj];
                        float w = xi + accp[j][m][r] + proj_b[c];
                        *(unsigned short*)(smem + ((t * W2B_ST + c) << 1)) = f2bf(w);
                        a += w; bb += w * w;
                    }
                    ps1[m][r] = a; ps2[m][r] = bb;
                }
            }
        }
        #pragma unroll
        for (int m = 0; m < 2; ++m) {
            #pragma unroll
            for (int r = 0; r < 4; ++r) {
                const int t = (mg * 2 + m) * 16 + sub * 4 + r;
                float a = ps1[m][r], bb = ps2[m][r];
                a += __shfl_xor(a, 1); bb += __shfl_xor(bb, 1);
                a += __shfl_xor(a, 2); bb += __shfl_xor(bb, 2);
                a += __shfl_xor(a, 4); bb += __shfl_xor(bb, 4);
                a += __shfl_xor(a, 8); bb += __shfl_xor(bb, 8);
                if (l15 == 0 && t < TOK) sPart[t * 4 + ng4] = make_float2(a, bb);
            }
        }
    }
    __syncthreads();

    // ---- LN2 finalize ----
    if (tid < TOK) {
        int t = tid;
        float2 q0 = sPart[t * 4 + 0], q1 = sPart[t * 4 + 1];
        float2 q2 = sPart[t * 4 + 2], q3 = sPart[t * 4 + 3];
        float s = q0.x + q1.x + q2.x + q3.x;
        float ss = q0.y + q1.y + q2.y + q3.y;
        float m = s * (1.f / 256.f);
        float var = ss * (1.f / 256.f) - m * m;
        sM[t] = m; sR[t] = rsqrtf(var + 1e-5f);
    }
    __syncthreads();

    // ---- P8: LN2 normalize -> n2F frags (R2); zero pad rows ----
    for (int e = tid; e < 2048; e += 512) {
        int t = e & 63, cb = e >> 6;
        char* dst = smem + OFF_N2F + (((t >> 4) * 8 + (cb >> 2)) << 10)
                  + (((((cb & 3) << 4) | (t & 15))) << 4);
        if (t < TOK) {
            u16x8 wv = *(const u16x8*)(smem + ((t * W2B_ST + cb * 8) << 1));
            int c = cb * 8;
            float4 ga = *(const float4*)(ln2_g + c), gb = *(const float4*)(ln2_g + c + 4);
            float4 ba = *(const float4*)(ln2_b + c), bb = *(const float4*)(ln2_b + c + 4);
            float m = sM[t], rs = sR[t];
            u16x8 o;
            o[0] = f2bf((bfu(wv[0]) - m) * rs * ga.x + ba.x);
            o[1] = f2bf((bfu(wv[1]) - m) * rs * ga.y + ba.y);
            o[2] = f2bf((bfu(wv[2]) - m) * rs * ga.z + ba.z);
            o[3] = f2bf((bfu(wv[3]) - m) * rs * ga.w + ba.w);
            o[4] = f2bf((bfu(wv[4]) - m) * rs * gb.x + bb.x);
            o[5] = f2bf((bfu(wv[5]) - m) * rs * gb.y + bb.y);
            o[6] = f2bf((bfu(wv[6]) - m) * rs * gb.z + bb.z);
            o[7] = f2bf((bfu(wv[7]) - m) * rs * gb.w + bb.w);
            *(u16x8*)dst = o;
        } else {
            u16x8 z = {0, 0, 0, 0, 0, 0, 0, 0};
            *(u16x8*)dst = z;
        }
    }
    __syncthreads();

    // ---- P9: MLP in 4 col-quarters of HID; HM quarter ping-pongs @ OFF_HMQ ----
    f32x4 acc2[4][2];
    #pragma unroll
    for (int j = 0; j < 4; ++j) { acc2[j][0] = z4; acc2[j][1] = z4; }

    for (int q = 0; q < 4; ++q) {
        // MLP1 quarter: n2 @ w1[:, q*128 +: 128] + b1, GELU -> HM_q
        #pragma unroll
        for (int i2 = 0; i2 < 2; ++i2) {
            const int ntg = q * 8 + ng4 * 2 + i2;
            bf16x8 bF[8];
            #pragma unroll
            for (int kt = 0; kt < 8; ++kt)
                bF[kt] = *(const bf16x8*)(ws + ((size_t)(WS_W1_BLK + ntg * 8 + kt) << 10) + lane * 16);
            f32x4 acc[2] = {z4, z4};
            #pragma unroll
            for (int kt = 0; kt < 8; ++kt) {
                bf16x8 a0 = *(const bf16x8*)(smem + OFF_N2F + (((mg * 2 + 0) * 8 + kt) << 10) + lane * 16);
                bf16x8 a1 = *(const bf16x8*)(smem + OFF_N2F + (((mg * 2 + 1) * 8 + kt) << 10) + lane * 16);
                acc[0] = mfma16(a0, bF[kt], acc[0]);
                acc[1] = mfma16(a1, bF[kt], acc[1]);
            }
            const int cl = (ng4 * 2 + i2) * 16 + l15;   // 0..127
            const float bias = b1[q * 128 + cl];
            #pragma unroll
            for (int m = 0; m < 2; ++m)
                #pragma unroll
                for (int r = 0; r < 4; ++r) {
                    int t = (mg * 2 + m) * 16 + sub * 4 + r;
                    if (t < TOK) {
                        float v = acc[m][r] + bias;
                        float u = v * (1.5957691216f + 0.07135481627f * v * v);
                        float g = v / (1.f + __expf(-u));
                        *(unsigned short*)(smem + frOffH(t, cl)) = f2bf(g);
                    }
                }
        }
        __syncthreads();   // HM_q ready

        // MLP2 partial: acc2 += HM_q @ w2[q*128 +: 128, :]
        {
            bf16x8 hf[2][4];
            #pragma unroll
            for (int m = 0; m < 2; ++m)
                #pragma unroll
                for (int k = 0; k < 4; ++k)
                    hf[m][k] = *(const bf16x8*)(smem + OFF_HMQ + (((mg * 2 + m) * 4 + k) << 10) + lane * 16);
            #pragma unroll
            for (int j = 0; j < 4; ++j) {
                #pragma unroll
                for (int k = 0; k < 4; ++k) {
                    bf16x8 bf = *(const bf16x8*)(ws + ((size_t)(WS_W2_BLK + (ng4 * 4 + j) * 16 + q * 4 + k) << 10) + lane * 16);
                    acc2[j][0] = mfma16(hf[0][k], bf, acc2[j][0]);
                    acc2[j][1] = mfma16(hf[1][k], bf, acc2[j][1]);
                }
            }
        }
        __syncthreads();   // HM_q region reusable
    }

    // ---- P10: final epilogue: y = win2 + mlp2 + b2 (direct global scatter) ----
    #pragma unroll
    for (int m = 0; m < 2; ++m) {
        #pragma unroll
        for (int r = 0; r < 4; ++r) {
            const int t = (mg * 2 + m) * 16 + sub * 4 + r;
            if (t < TOK) {
                const int i7 = t / 7, jj = t - i7 * 7;
                #pragma unroll
                for (int j = 0; j < 4; ++j) {
                    const int c = (ng4 * 4 + j) * 16 + l15;
                    float w = bfu(*(unsigned short*)(smem + ((t * W2B_ST + c) << 1)))
                            + acc2[j][m][r] + b2[c];
                    y[xbase + ((size_t)c * IMG + row0 + i7) * IMG + col0 + jj] = w;
                }
            }
        }
    }
}

extern "C" void kernel_launch(void* const* d_in, const int* in_sizes, int n_in,
                              void* d_out, int out_size, void* d_ws, size_t ws_size,
                              hipStream_t stream) {
    const float* x      = (const float*)d_in[0];
    const float* ln1_g  = (const float*)d_in[1];
    const float* ln1_b  = (const float*)d_in[2];
    const float* qkv_w  = (const float*)d_in[3];
    const float* qkv_b  = (const float*)d_in[4];
    const float* proj_w = (const float*)d_in[5];
    const float* proj_b = (const float*)d_in[6];
    const float* ln2_g  = (const float*)d_in[7];
    const float* ln2_b  = (const float*)d_in[8];
    const float* w1     = (const float*)d_in[9];
    const float* b1     = (const float*)d_in[10];
    const float* w2     = (const float*)d_in[11];
    const float* b2     = (const float*)d_in[12];

    hipLaunchKernelGGL(prepack, dim3(1024), dim3(64), 0, stream,
                       qkv_w, proj_w, w1, w2, (char*)d_ws);
    hipLaunchKernelGGL(swin_block, dim3(NWIN), dim3(512), 0, stream,
                       x, ln1_g, ln1_b, qkv_b, proj_b, ln2_g, ln2_b, b1, b2,
                       (const char*)d_ws, (float*)d_out);
}

// Round 7
// 1640.059 us; speedup vs baseline: 1.0117x; 1.0117x over previous
//
#include <hip/hip_runtime.h>
#include <hip/hip_bf16.h>

typedef __bf16 bf16x8 __attribute__((ext_vector_type(8)));
typedef float  f32x4  __attribute__((ext_vector_type(4)));
typedef unsigned short u16x8 __attribute__((ext_vector_type(8)));
typedef unsigned short u16x4 __attribute__((ext_vector_type(4)));

#define CH    256
#define IMG   112
#define WSZ   7
#define TOK   49
#define NWIN  4096

// ---- LDS arena (77,824 B total -> 2 blocks/CU) ----
// R1 [0, 42496): n1F frags (32K)  ->  win2b bf16 (25,872) + HM quarter (16K @25888)
// R2 [42496, 75264): sXb bf16 (25,872) -> head bufs (Q 8K|K 8K|V 8K|P 7K; O over Q) -> n2F (32K)
// misc [75264, 77824): sM 256 | sR 256 | sPart 2048
#define OFF_R1   0
#define W2B_ST   264
#define OFF_HMQ  25888
#define OFF_R2   42496
#define SXB_ST   264
#define OFF_QH   (OFF_R2 + 0)
#define OFF_KH   (OFF_R2 + 8192)
#define OFF_VH   (OFF_R2 + 16384)
#define OFF_PH   (OFF_R2 + 24576)
#define OFF_OH   (OFF_R2 + 0)
#define OFF_N2F  OFF_R2
#define OFF_MISC 75264
#define SMEM_SZ  77824

// ---- d_ws layout: bf16 B-fragment blocks, 1KB each ----
#define WS_PROJ_BLK 384
#define WS_W1_BLK   512
#define WS_W2_BLK   768

__device__ __forceinline__ unsigned short f2bf(float f) {
    __bf16 h = (__bf16)f;
    return __builtin_bit_cast(unsigned short, h);
}
__device__ __forceinline__ float bfu(unsigned short u) {
    return __uint_as_float(((unsigned)u) << 16);
}
__device__ __forceinline__ f32x4 mfma16(bf16x8 a, bf16x8 b, f32x4 c) {
    return __builtin_amdgcn_mfma_f32_16x16x32_bf16(a, b, c, 0, 0, 0);
}

// frag-block element byte offsets
__device__ __forceinline__ int frOff2(int base, int t, int c) {   // 64-col arena
    return base + (((t >> 4) * 2 + (c >> 5)) << 10)
                + (((((c >> 3) & 3) << 4) | (t & 15)) << 4) + ((c & 7) << 1);
}
__device__ __forceinline__ int frOffT2(int base, int d, int s) {  // V^T 64x64 arena
    return base + (((d >> 4) * 2 + (s >> 5)) << 10)
                + (((((s >> 3) & 3) << 4) | (d & 15)) << 4) + ((s & 7) << 1);
}
__device__ __forceinline__ int frOffH(int t, int c) {             // 128-col HM quarter
    return OFF_HMQ + (((t >> 4) * 4 + (c >> 5)) << 10)
                + (((((c >> 3) & 3) << 4) | (t & 15)) << 4) + ((c & 7) << 1);
}

// ---------------- prepack: fp32 weights -> bf16 B-fragment blocks in d_ws ----------------
extern "C" __global__ __launch_bounds__(64)
void prepack(const float* __restrict__ qkv_w, const float* __restrict__ proj_w,
             const float* __restrict__ w1, const float* __restrict__ w2,
             char* __restrict__ ws)
{
    const int blk = blockIdx.x, l = threadIdx.x;
    const float* W; int nt, kt, ncols;
    if (blk < WS_PROJ_BLK)      { W = qkv_w;  int i = blk;               nt = i >> 3; kt = i & 7;  ncols = 768; }
    else if (blk < WS_W1_BLK)   { W = proj_w; int i = blk - WS_PROJ_BLK; nt = i >> 3; kt = i & 7;  ncols = 256; }
    else if (blk < WS_W2_BLK)   { W = w1;     int i = blk - WS_W1_BLK;   nt = i >> 3; kt = i & 7;  ncols = 512; }
    else                        { W = w2;     int i = blk - WS_W2_BLK;   nt = i >> 4; kt = i & 15; ncols = 256; }
    const int n  = nt * 16 + (l & 15);
    const int k0 = kt * 32 + (l >> 4) * 8;
    u16x8 o;
    #pragma unroll
    for (int j = 0; j < 8; ++j) o[j] = f2bf(W[(size_t)(k0 + j) * ncols + n]);
    *(u16x8*)(ws + (size_t)blk * 1024 + l * 16) = o;
}

// ---------------- main fused block: 8 waves; compiler free on VGPR (spill-free codegen) ----------------
extern "C" __global__ __launch_bounds__(512, 1)
void swin_block(const float* __restrict__ x,
                const float* __restrict__ ln1_g, const float* __restrict__ ln1_b,
                const float* __restrict__ qkv_b,
                const float* __restrict__ proj_b,
                const float* __restrict__ ln2_g, const float* __restrict__ ln2_b,
                const float* __restrict__ b1, const float* __restrict__ b2,
                const char* __restrict__ ws,
                float* __restrict__ y)
{
    __shared__ __align__(16) char smem[SMEM_SZ];
    float*  sM    = (float*)(smem + OFF_MISC);
    float*  sR    = (float*)(smem + OFF_MISC + 256);
    float2* sPart = (float2*)(smem + OFF_MISC + 512);

    const int tid  = threadIdx.x;
    const int wid  = tid >> 6;       // 0..7
    const int lane = tid & 63;
    const int sub  = lane >> 4;
    const int l15  = lane & 15;
    const int mg   = wid >> 2;       // m-half 0..1
    const int ng4  = wid & 3;        // n-group 0..3
    const int ah   = wid & 3;        // attn row-quarter
    const int chh  = wid >> 2;       // attn col-half

    const int n  = blockIdx.x;
    const int b  = n >> 8;
    const int wh = (n >> 4) & 15;
    const int ww = n & 15;
    const int row0 = wh * WSZ, col0 = ww * WSZ;
    const size_t xbase = (size_t)b * CH * IMG * IMG;

    const f32x4 z4 = {0.f, 0.f, 0.f, 0.f};

    // ---- P0: stage x -> sXb (bf16 [t][c], stride 264) ----
    for (int e = tid; e < TOK * CH; e += 512) {
        int j = e % 7; int rem = e / 7; int i = rem % 7; int c = rem / 7;
        int t = i * 7 + j;
        *(unsigned short*)(smem + OFF_R2 + ((t * SXB_ST + c) << 1)) =
            f2bf(x[xbase + ((size_t)c * IMG + row0 + i) * IMG + col0 + j]);
    }
    __syncthreads();

    // ---- P1: LN1 stats (from bf16 x) ----
    for (int t = wid; t < TOK; t += 8) {
        u16x4 v4 = *(const u16x4*)(smem + OFF_R2 + ((t * SXB_ST + lane * 4) << 1));
        float a0 = bfu(v4[0]), a1 = bfu(v4[1]), a2 = bfu(v4[2]), a3 = bfu(v4[3]);
        float s1 = a0 + a1 + a2 + a3;
        float s2 = a0 * a0 + a1 * a1 + a2 * a2 + a3 * a3;
        #pragma unroll
        for (int off = 32; off > 0; off >>= 1) {
            s1 += __shfl_xor(s1, off);
            s2 += __shfl_xor(s2, off);
        }
        if (lane == 0) {
            float m = s1 * (1.f / 256.f);
            float var = s2 * (1.f / 256.f) - m * m;
            sM[t] = m; sR[t] = rsqrtf(var + 1e-5f);
        }
    }
    __syncthreads();

    // ---- P2: LN1 normalize -> n1F frags (R1); zero pad rows ----
    for (int e = tid; e < 2048; e += 512) {
        int t = e & 63, cb = e >> 6;
        char* dst = smem + OFF_R1 + (((t >> 4) * 8 + (cb >> 2)) << 10)
                  + (((((cb & 3) << 4) | (t & 15))) << 4);
        if (t < TOK) {
            u16x8 xv = *(const u16x8*)(smem + OFF_R2 + ((t * SXB_ST + cb * 8) << 1));
            int c = cb * 8;
            float4 ga = *(const float4*)(ln1_g + c), gb = *(const float4*)(ln1_g + c + 4);
            float4 ba = *(const float4*)(ln1_b + c), bb = *(const float4*)(ln1_b + c + 4);
            float m = sM[t], rs = sR[t];
            u16x8 o;
            o[0] = f2bf((bfu(xv[0]) - m) * rs * ga.x + ba.x);
            o[1] = f2bf((bfu(xv[1]) - m) * rs * ga.y + ba.y);
            o[2] = f2bf((bfu(xv[2]) - m) * rs * ga.z + ba.z);
            o[3] = f2bf((bfu(xv[3]) - m) * rs * ga.w + ba.w);
            o[4] = f2bf((bfu(xv[4]) - m) * rs * gb.x + bb.x);
            o[5] = f2bf((bfu(xv[5]) - m) * rs * gb.y + bb.y);
            o[6] = f2bf((bfu(xv[6]) - m) * rs * gb.z + bb.z);
            o[7] = f2bf((bfu(xv[7]) - m) * rs * gb.w + bb.w);
            *(u16x8*)dst = o;
        } else {
            u16x8 z = {0, 0, 0, 0, 0, 0, 0, 0};
            *(u16x8*)dst = z;
        }
    }
    __syncthreads();

    // ---- P3/P4: head loop: QKV_h -> attn_h -> proj partial (acc in regs) ----
    f32x4 accp[4][2];
    #pragma unroll
    for (int j = 0; j < 4; ++j) { accp[j][0] = z4; accp[j][1] = z4; }

    for (int h = 0; h < 4; ++h) {
        // -- QKV GEMM for head h: wave (mg,ng4) does 1 ntile each of Q,K,V --
        #pragma unroll
        for (int mtx = 0; mtx < 3; ++mtx) {
            const int ntg = mtx * 16 + h * 4 + ng4;
            bf16x8 bF[8];
            #pragma unroll
            for (int kt = 0; kt < 8; ++kt)
                bF[kt] = *(const bf16x8*)(ws + ((size_t)(ntg * 8 + kt) << 10) + lane * 16);
            f32x4 acc[2] = {z4, z4};
            #pragma unroll
            for (int kt = 0; kt < 8; ++kt) {
                bf16x8 a0 = *(const bf16x8*)(smem + OFF_R1 + (((mg * 2 + 0) * 8 + kt) << 10) + lane * 16);
                bf16x8 a1 = *(const bf16x8*)(smem + OFF_R1 + (((mg * 2 + 1) * 8 + kt) << 10) + lane * 16);
                acc[0] = mfma16(a0, bF[kt], acc[0]);
                acc[1] = mfma16(a1, bF[kt], acc[1]);
            }
            const int cl = ng4 * 16 + l15;                 // head-local col 0..63
            const float bias = qkv_b[mtx * 256 + h * 64 + cl];
            if (mtx == 0) {
                #pragma unroll
                for (int m = 0; m < 2; ++m)
                    #pragma unroll
                    for (int r = 0; r < 4; ++r) {
                        int t = (mg * 2 + m) * 16 + sub * 4 + r;
                        *(unsigned short*)(smem + frOff2(OFF_QH, t, cl)) = f2bf((acc[m][r] + bias) * 0.125f);
                    }
            } else if (mtx == 1) {
                #pragma unroll
                for (int m = 0; m < 2; ++m)
                    #pragma unroll
                    for (int r = 0; r < 4; ++r) {
                        int t = (mg * 2 + m) * 16 + sub * 4 + r;
                        *(unsigned short*)(smem + frOff2(OFF_KH, t, cl)) = f2bf(acc[m][r] + bias);
                    }
            } else {
                #pragma unroll
                for (int m = 0; m < 2; ++m)
                    #pragma unroll
                    for (int r = 0; r < 4; ++r) {
                        int t = (mg * 2 + m) * 16 + sub * 4 + r;
                        *(unsigned short*)(smem + frOffT2(OFF_VH, cl, t)) = f2bf(acc[m][r] + bias);
                    }
            }
        }
        __syncthreads();   // A: Q/K/V ready

        // -- QK^T: wave (ah, chh): rows ah*16+:16, cols chh*32+:32 --
        f32x4 sc[2] = {z4, z4};
        {
            bf16x8 qf[2], kf[2][2];
            #pragma unroll
            for (int k2 = 0; k2 < 2; ++k2)
                qf[k2] = *(const bf16x8*)(smem + OFF_QH + ((ah * 2 + k2) << 10) + lane * 16);
            #pragma unroll
            for (int nt = 0; nt < 2; ++nt)
                #pragma unroll
                for (int k2 = 0; k2 < 2; ++k2)
                    kf[nt][k2] = *(const bf16x8*)(smem + OFF_KH + (((chh * 2 + nt) * 2 + k2) << 10) + lane * 16);
            #pragma unroll
            for (int k2 = 0; k2 < 2; ++k2) {
                sc[0] = mfma16(qf[k2], kf[0][k2], sc[0]);
                sc[1] = mfma16(qf[k2], kf[1][k2], sc[1]);
            }
        }
        float mxl[4];
        #pragma unroll
        for (int r = 0; r < 4; ++r) {
            const int t = ah * 16 + sub * 4 + r;
            float v0 = sc[0][r];
            float v1 = (chh == 1 && l15 > 0) ? -1e30f : sc[1][r];   // mask s>=49
            sc[1][r] = v1;
            float mx = fmaxf(v0, v1);
            mx = fmaxf(mx, __shfl_xor(mx, 1));
            mx = fmaxf(mx, __shfl_xor(mx, 2));
            mx = fmaxf(mx, __shfl_xor(mx, 4));
            mx = fmaxf(mx, __shfl_xor(mx, 8));
            mxl[r] = mx;
            float e0 = __expf(v0 - mx), e1 = __expf(v1 - mx);
            float sm = e0 + e1;
            sm += __shfl_xor(sm, 1);
            sm += __shfl_xor(sm, 2);
            sm += __shfl_xor(sm, 4);
            sm += __shfl_xor(sm, 8);
            if (l15 == 0 && t < TOK) sPart[t * 2 + chh] = make_float2(mx, sm);
        }
        __syncthreads();   // B: partials ready

        // -- merge partials + write P (bf16, [t][s], stride 144B) --
        #pragma unroll
        for (int r = 0; r < 4; ++r) {
            const int t = ah * 16 + sub * 4 + r;
            if (t < TOK) {
                float2 p0 = sPart[t * 2 + 0], p1 = sPart[t * 2 + 1];
                float M = fmaxf(p0.x, p1.x);
                float denom = p0.y * __expf(p0.x - M) + p1.y * __expf(p1.x - M);
                float scale = __expf(mxl[r] - M) / denom;
                unsigned short* pr = (unsigned short*)(smem + OFF_PH + t * 144);
                pr[chh * 32 + l15]      = f2bf(__expf(sc[0][r] - mxl[r]) * scale);
                pr[chh * 32 + 16 + l15] = f2bf(__expf(sc[1][r] - mxl[r]) * scale);
            }
        }
        __syncthreads();   // C: P ready (Q also fully consumed)

        // -- PV: wave (ah, nh=chh): O rows ah*16+:16, cols chh*32+:32 --
        {
            bf16x8 pf[2], vf[2][2];
            int rowc = ah * 16 + l15; rowc = rowc > 48 ? 48 : rowc;
            #pragma unroll
            for (int k2 = 0; k2 < 2; ++k2)
                pf[k2] = *(const bf16x8*)(smem + OFF_PH + rowc * 144 + ((k2 * 32 + sub * 8) << 1));
            #pragma unroll
            for (int nt = 0; nt < 2; ++nt)
                #pragma unroll
                for (int k2 = 0; k2 < 2; ++k2)
                    vf[nt][k2] = *(const bf16x8*)(smem + OFF_VH + (((chh * 2 + nt) * 2 + k2) << 10) + lane * 16);
            f32x4 oc[2] = {z4, z4};
            #pragma unroll
            for (int k2 = 0; k2 < 2; ++k2) {
                oc[0] = mfma16(pf[k2], vf[0][k2], oc[0]);
                oc[1] = mfma16(pf[k2], vf[1][k2], oc[1]);
            }
            #pragma unroll
            for (int nt = 0; nt < 2; ++nt)
                #pragma unroll
                for (int r = 0; r < 4; ++r) {
                    int t = ah * 16 + sub * 4 + r;
                    int c = (chh * 2 + nt) * 16 + l15;
                    *(unsigned short*)(smem + frOff2(OFF_OH, t, c)) = f2bf(oc[nt][r]);
                }
        }
        __syncthreads();   // D: O_h ready

        // -- proj partial: wave (mg,ng4): accp[j][m] += O_h @ Wproj[h*64+:64, ng4*64+:64] --
        {
            bf16x8 aO[2][2];
            #pragma unroll
            for (int m = 0; m < 2; ++m)
                #pragma unroll
                for (int k2 = 0; k2 < 2; ++k2)
                    aO[m][k2] = *(const bf16x8*)(smem + OFF_OH + (((mg * 2 + m) * 2 + k2) << 10) + lane * 16);
            #pragma unroll
            for (int j = 0; j < 4; ++j) {
                bf16x8 b0 = *(const bf16x8*)(ws + ((size_t)(WS_PROJ_BLK + (ng4 * 4 + j) * 8 + h * 2 + 0) << 10) + lane * 16);
                bf16x8 b1 = *(const bf16x8*)(ws + ((size_t)(WS_PROJ_BLK + (ng4 * 4 + j) * 8 + h * 2 + 1) << 10) + lane * 16);
                #pragma unroll
                for (int m = 0; m < 2; ++m) {
                    accp[j][m] = mfma16(aO[m][0], b0, accp[j][m]);
                    accp[j][m] = mfma16(aO[m][1], b1, accp[j][m]);
                }
            }
        }
        __syncthreads();   // E: O_h region free for next head's Q
    }

    // ---- P6: proj epilogue: win2 = x + proj + bias -> win2b (bf16); LN2 partial stats ----
    {
        float ps1[2][4], ps2[2][4];
        #pragma unroll
        for (int m = 0; m < 2; ++m) {
            #pragma unroll
            for (int r = 0; r < 4; ++r) {
                const int t = (mg * 2 + m) * 16 + sub * 4 + r;
                ps1[m][r] = 0.f; ps2[m][r] = 0.f;
                if (t < TOK) {
                    const int i7 = t / 7, jj = t - i7 * 7;
                    float a = 0.f, bb = 0.f;
                    #pragma unroll
                    for (int j = 0; j < 4; ++j) {
                        const int c = (ng4 * 4 + j) * 16 + l15;
                        float xi = x[xbase + ((size_t)c * IMG + row0 + i7) * IMG + col0 + jj];
                        float w = xi + accp[j][m][r] + proj_b[c];
                        *(unsigned short*)(smem + ((t * W2B_ST + c) << 1)) = f2bf(w);
                        a += w; bb += w * w;
                    }
                    ps1[m][r] = a; ps2[m][r] = bb;
                }
            }
        }
        #pragma unroll
        for (int m = 0; m < 2; ++m) {
            #pragma unroll
            for (int r = 0; r < 4; ++r) {
                const int t = (mg * 2 + m) * 16 + sub * 4 + r;
                float a = ps1[m][r], bb = ps2[m][r];
                a += __shfl_xor(a, 1); bb += __shfl_xor(bb, 1);
                a += __shfl_xor(a, 2); bb += __shfl_xor(bb, 2);
                a += __shfl_xor(a, 4); bb += __shfl_xor(bb, 4);
                a += __shfl_xor(a, 8); bb += __shfl_xor(bb, 8);
                if (l15 == 0 && t < TOK) sPart[t * 4 + ng4] = make_float2(a, bb);
            }
        }
    }
    __syncthreads();

    // ---- LN2 finalize ----
    if (tid < TOK) {
        int t = tid;
        float2 q0 = sPart[t * 4 + 0], q1 = sPart[t * 4 + 1];
        float2 q2 = sPart[t * 4 + 2], q3 = sPart[t * 4 + 3];
        float s = q0.x + q1.x + q2.x + q3.x;
        float ss = q0.y + q1.y + q2.y + q3.y;
        float m = s * (1.f / 256.f);
        float var = ss * (1.f / 256.f) - m * m;
        sM[t] = m; sR[t] = rsqrtf(var + 1e-5f);
    }
    __syncthreads();

    // ---- P8: LN2 normalize -> n2F frags (R2); zero pad rows ----
    for (int e = tid; e < 2048; e += 512) {
        int t = e & 63, cb = e >> 6;
        char* dst = smem + OFF_N2F + (((t >> 4) * 8 + (cb >> 2)) << 10)
                  + (((((cb & 3) << 4) | (t & 15))) << 4);
        if (t < TOK) {
            u16x8 wv = *(const u16x8*)(smem + ((t * W2B_ST + cb * 8) << 1));
            int c = cb * 8;
            float4 ga = *(const float4*)(ln2_g + c), gb = *(const float4*)(ln2_g + c + 4);
            float4 ba = *(const float4*)(ln2_b + c), bb = *(const float4*)(ln2_b + c + 4);
            float m = sM[t], rs = sR[t];
            u16x8 o;
            o[0] = f2bf((bfu(wv[0]) - m) * rs * ga.x + ba.x);
            o[1] = f2bf((bfu(wv[1]) - m) * rs * ga.y + ba.y);
            o[2] = f2bf((bfu(wv[2]) - m) * rs * ga.z + ba.z);
            o[3] = f2bf((bfu(wv[3]) - m) * rs * ga.w + ba.w);
            o[4] = f2bf((bfu(wv[4]) - m) * rs * gb.x + bb.x);
            o[5] = f2bf((bfu(wv[5]) - m) * rs * gb.y + bb.y);
            o[6] = f2bf((bfu(wv[6]) - m) * rs * gb.z + bb.z);
            o[7] = f2bf((bfu(wv[7]) - m) * rs * gb.w + bb.w);
            *(u16x8*)dst = o;
        } else {
            u16x8 z = {0, 0, 0, 0, 0, 0, 0, 0};
            *(u16x8*)dst = z;
        }
    }
    __syncthreads();

    // ---- P9: MLP in 4 col-quarters of HID; HM quarter ping-pongs @ OFF_HMQ ----
    f32x4 acc2[4][2];
    #pragma unroll
    for (int j = 0; j < 4; ++j) { acc2[j][0] = z4; acc2[j][1] = z4; }

    for (int q = 0; q < 4; ++q) {
        // MLP1 quarter: n2 @ w1[:, q*128 +: 128] + b1, GELU -> HM_q
        #pragma unroll
        for (int i2 = 0; i2 < 2; ++i2) {
            const int ntg = q * 8 + ng4 * 2 + i2;
            bf16x8 bF[8];
            #pragma unroll
            for (int kt = 0; kt < 8; ++kt)
                bF[kt] = *(const bf16x8*)(ws + ((size_t)(WS_W1_BLK + ntg * 8 + kt) << 10) + lane * 16);
            f32x4 acc[2] = {z4, z4};
            #pragma unroll
            for (int kt = 0; kt < 8; ++kt) {
                bf16x8 a0 = *(const bf16x8*)(smem + OFF_N2F + (((mg * 2 + 0) * 8 + kt) << 10) + lane * 16);
                bf16x8 a1 = *(const bf16x8*)(smem + OFF_N2F + (((mg * 2 + 1) * 8 + kt) << 10) + lane * 16);
                acc[0] = mfma16(a0, bF[kt], acc[0]);
                acc[1] = mfma16(a1, bF[kt], acc[1]);
            }
            const int cl = (ng4 * 2 + i2) * 16 + l15;   // 0..127
            const float bias = b1[q * 128 + cl];
            #pragma unroll
            for (int m = 0; m < 2; ++m)
                #pragma unroll
                for (int r = 0; r < 4; ++r) {
                    int t = (mg * 2 + m) * 16 + sub * 4 + r;
                    if (t < TOK) {
                        float v = acc[m][r] + bias;
                        float u = v * (1.5957691216f + 0.07135481627f * v * v);
                        float g = v / (1.f + __expf(-u));
                        *(unsigned short*)(smem + frOffH(t, cl)) = f2bf(g);
                    }
                }
        }
        __syncthreads();   // HM_q ready

        // MLP2 partial: acc2 += HM_q @ w2[q*128 +: 128, :]
        {
            bf16x8 hf[2][4];
            #pragma unroll
            for (int m = 0; m < 2; ++m)
                #pragma unroll
                for (int k = 0; k < 4; ++k)
                    hf[m][k] = *(const bf16x8*)(smem + OFF_HMQ + (((mg * 2 + m) * 4 + k) << 10) + lane * 16);
            #pragma unroll
            for (int j = 0; j < 4; ++j) {
                #pragma unroll
                for (int k = 0; k < 4; ++k) {
                    bf16x8 bf = *(const bf16x8*)(ws + ((size_t)(WS_W2_BLK + (ng4 * 4 + j) * 16 + q * 4 + k) << 10) + lane * 16);
                    acc2[j][0] = mfma16(hf[0][k], bf, acc2[j][0]);
                    acc2[j][1] = mfma16(hf[1][k], bf, acc2[j][1]);
                }
            }
        }
        __syncthreads();   // HM_q region reusable
    }

    // ---- P10: final epilogue: y = win2 + mlp2 + b2 (direct global scatter) ----
    #pragma unroll
    for (int m = 0; m < 2; ++m) {
        #pragma unroll
        for (int r = 0; r < 4; ++r) {
            const int t = (mg * 2 + m) * 16 + sub * 4 + r;
            if (t < TOK) {
                const int i7 = t / 7, jj = t - i7 * 7;
                #pragma unroll
                for (int j = 0; j < 4; ++j) {
                    const int c = (ng4 * 4 + j) * 16 + l15;
                    float w = bfu(*(unsigned short*)(smem + ((t * W2B_ST + c) << 1)))
                            + acc2[j][m][r] + b2[c];
                    y[xbase + ((size_t)c * IMG + row0 + i7) * IMG + col0 + jj] = w;
                }
            }
        }
    }
}

extern "C" void kernel_launch(void* const* d_in, const int* in_sizes, int n_in,
                              void* d_out, int out_size, void* d_ws, size_t ws_size,
                              hipStream_t stream) {
    const float* x      = (const float*)d_in[0];
    const float* ln1_g  = (const float*)d_in[1];
    const float* ln1_b  = (const float*)d_in[2];
    const float* qkv_w  = (const float*)d_in[3];
    const float* qkv_b  = (const float*)d_in[4];
    const float* proj_w = (const float*)d_in[5];
    const float* proj_b = (const float*)d_in[6];
    const float* ln2_g  = (const float*)d_in[7];
    const float* ln2_b  = (const float*)d_in[8];
    const float* w1     = (const float*)d_in[9];
    const float* b1     = (const float*)d_in[10];
    const float* w2     = (const float*)d_in[11];
    const float* b2     = (const float*)d_in[12];

    hipLaunchKernelGGL(prepack, dim3(1024), dim3(64), 0, stream,
                       qkv_w, proj_w, w1, w2, (char*)d_ws);
    hipLaunchKernelGGL(swin_block, dim3(NWIN), dim3(512), 0, stream,
                       x, ln1_g, ln1_b, qkv_b, proj_b, ln2_g, ln2_b, b1, b2,
                       (const char*)d_ws, (float*)d_out);
}

// Round 8
// 1012.332 us; speedup vs baseline: 1.6390x; 1.6201x over previous
//
#include <hip/hip_runtime.h>
#include <hip/hip_bf16.h>

typedef __bf16 bf16x8 __attribute__((ext_vector_type(8)));
typedef float  f32x4  __attribute__((ext_vector_type(4)));
typedef unsigned short u16x8 __attribute__((ext_vector_type(8)));

#define CH    256
#define IMG   112
#define WSZ   7
#define TOK   49
#define NWIN  4096
#define HID   512
#define NTHR  768

#define SX_ST 260          // f32 row stride for sX / sW staging

// ---- LDS arena (byte offsets), time-multiplexed (identical to round 3) ----
#define OFF_V    0
#define OFF_AF   51200
#define OFF_P    51200
#define PSZ      7168
#define OFF_Q    83968
#define OFF_HM   83968
#define OFF_K    116736
#define OFF_OF   116736
#define OFF_MR   149504     // sM[64], sR[64]
#define OFF_PRM  150016     // sG1,sB1,sG2,sB2 (each 256 f32)
#define SMEM_SZ  154112

// ---- d_ws layout: bf16 B-fragment blocks, 1KB each ----
#define WS_PROJ_BLK 384
#define WS_W1_BLK   512
#define WS_W2_BLK   768

__device__ __forceinline__ unsigned short f2bf(float f) {
    __bf16 h = (__bf16)f;
    return __builtin_bit_cast(unsigned short, h);
}

__device__ __forceinline__ f32x4 mfma16(bf16x8 a, bf16x8 b, f32x4 c) {
    return __builtin_amdgcn_mfma_f32_16x16x32_bf16(a, b, c, 0, 0, 0);
}

__device__ __forceinline__ int frOff(int base, int t, int c) {
    return base + (((t >> 4) * 8 + (c >> 5)) << 10)
                + (((((c >> 3) & 3) << 4) | (t & 15)) << 4)
                + ((c & 7) << 1);
}
__device__ __forceinline__ int frOffT(int base, int c, int t) {
    return base + ((((c >> 4) << 1) + (t >> 5)) << 10)
                + (((((t >> 3) & 3) << 4) | (c & 15)) << 4)
                + ((t & 7) << 1);
}

// ---------------- prepack: fp32 weights -> bf16 B-fragment blocks in d_ws ----------------
extern "C" __global__ __launch_bounds__(64)
void prepack(const float* __restrict__ qkv_w, const float* __restrict__ proj_w,
             const float* __restrict__ w1, const float* __restrict__ w2,
             char* __restrict__ ws)
{
    const int blk = blockIdx.x, l = threadIdx.x;
    const float* W; int nt, kt, ncols;
    if (blk < WS_PROJ_BLK)      { W = qkv_w;  int i = blk;               nt = i >> 3; kt = i & 7;  ncols = 768; }
    else if (blk < WS_W1_BLK)   { W = proj_w; int i = blk - WS_PROJ_BLK; nt = i >> 3; kt = i & 7;  ncols = 256; }
    else if (blk < WS_W2_BLK)   { W = w1;     int i = blk - WS_W1_BLK;   nt = i >> 3; kt = i & 7;  ncols = 512; }
    else                        { W = w2;     int i = blk - WS_W2_BLK;   nt = i >> 4; kt = i & 15; ncols = 256; }
    const int n  = nt * 16 + (l & 15);
    const int k0 = kt * 32 + (l >> 4) * 8;
    u16x8 o;
    #pragma unroll
    for (int j = 0; j < 8; ++j) o[j] = f2bf(W[(size_t)(k0 + j) * ncols + n]);
    *(u16x8*)(ws + (size_t)blk * 1024 + l * 16) = o;
}

// ---------------- main fused block: 12 waves, 1 block/CU (3 waves/SIMD) ----------------
extern "C" __global__ __launch_bounds__(NTHR, 1)
void swin_block(const float* __restrict__ x,
                const float* __restrict__ ln1_g, const float* __restrict__ ln1_b,
                const float* __restrict__ qkv_b,
                const float* __restrict__ proj_b,
                const float* __restrict__ ln2_g, const float* __restrict__ ln2_b,
                const float* __restrict__ b1, const float* __restrict__ b2,
                const char* __restrict__ ws,
                float* __restrict__ y)
{
    __shared__ __align__(16) char smem[SMEM_SZ];
    float* sX = (float*)(smem + 0);          // also sW later
    float* sM = (float*)(smem + OFF_MR);
    float* sR = sM + 64;
    float* sG1 = (float*)(smem + OFF_PRM);
    float* sB1 = sG1 + 256;
    float* sG2 = sB1 + 256;
    float* sB2 = sG2 + 256;

    const int tid  = threadIdx.x;
    const int wid  = tid >> 6;       // 0..11
    const int lane = tid & 63;
    const int sub  = lane >> 4;
    const int l15  = lane & 15;
    const int mg   = wid / 6;        // m-group 0..1 (row-tiles mg*2, mg*2+1)
    const int ng6  = wid % 6;        // n-group 0..5

    const int n  = blockIdx.x;
    const int b  = n >> 8;
    const int wh = (n >> 4) & 15;
    const int ww = n & 15;
    const int row0 = wh * WSZ, col0 = ww * WSZ;
    const size_t xbase = (size_t)b * CH * IMG * IMG;

    const f32x4 z4 = {0.f, 0.f, 0.f, 0.f};

    // ---- P0: stage x -> sX; load LN params ----
    for (int e = tid; e < TOK * CH; e += NTHR) {
        int j = e % 7; int rem = e / 7; int i = rem % 7; int c = rem / 7;
        sX[(i * 7 + j) * SX_ST + c] = x[xbase + ((size_t)c * IMG + row0 + i) * IMG + col0 + j];
    }
    if (tid < 512) {
        int t2 = tid & 255;
        if (tid < 256) { sG1[t2] = ln1_g[t2]; sB1[t2] = ln1_b[t2]; }
        else           { sG2[t2] = ln2_g[t2]; sB2[t2] = ln2_b[t2]; }
    }
    __syncthreads();   // 1

    // ---- P1: LN1 stats ----
    for (int t = wid; t < TOK; t += 12) {
        const float4 v = *(const float4*)&sX[t * SX_ST + lane * 4];
        float s1 = v.x + v.y + v.z + v.w;
        float s2 = v.x * v.x + v.y * v.y + v.z * v.z + v.w * v.w;
        #pragma unroll
        for (int off = 32; off > 0; off >>= 1) {
            s1 += __shfl_xor(s1, off);
            s2 += __shfl_xor(s2, off);
        }
        if (lane == 0) {
            float m = s1 * (1.f / 256.f);
            float var = s2 * (1.f / 256.f) - m * m;
            sM[t] = m; sR[t] = rsqrtf(var + 1e-5f);
        }
    }
    __syncthreads();   // 2

    // ---- P2: normalize -> n1F fragment blocks; zero pad rows ----
    for (int e = tid; e < 2048; e += NTHR) {
        int t = e & 63, cb = e >> 6;
        char* dst = smem + OFF_AF + (((t >> 4) * 8 + (cb >> 2)) << 10)
                  + (((((cb & 3) << 4) | (t & 15))) << 4);
        if (t < TOK) {
            const float* xr = sX + t * SX_ST + cb * 8;
            float4 xa = *(const float4*)xr;
            float4 xb = *(const float4*)(xr + 4);
            float m = sM[t], rs = sR[t];
            int c = cb * 8;
            u16x8 o;
            o[0] = f2bf((xa.x - m) * rs * sG1[c + 0] + sB1[c + 0]);
            o[1] = f2bf((xa.y - m) * rs * sG1[c + 1] + sB1[c + 1]);
            o[2] = f2bf((xa.z - m) * rs * sG1[c + 2] + sB1[c + 2]);
            o[3] = f2bf((xa.w - m) * rs * sG1[c + 3] + sB1[c + 3]);
            o[4] = f2bf((xb.x - m) * rs * sG1[c + 4] + sB1[c + 4]);
            o[5] = f2bf((xb.y - m) * rs * sG1[c + 5] + sB1[c + 5]);
            o[6] = f2bf((xb.z - m) * rs * sG1[c + 6] + sB1[c + 6]);
            o[7] = f2bf((xb.w - m) * rs * sG1[c + 7] + sB1[c + 7]);
            *(u16x8*)dst = o;
        } else {
            u16x8 z = {0, 0, 0, 0, 0, 0, 0, 0};
            *(u16x8*)dst = z;
        }
    }
    __syncthreads();   // 3

    // ---- P3: QKV GEMM (M=64,N=768,K=256); wave (mg,ng6): ntg = ng6*8 + i, i<8 ----
    {
        bf16x8 aF[2][8];
        #pragma unroll
        for (int m = 0; m < 2; ++m)
            #pragma unroll
            for (int kt = 0; kt < 8; ++kt)
                aF[m][kt] = *(const bf16x8*)(smem + OFF_AF + (((mg * 2 + m) * 8 + kt) << 10) + lane * 16);

        auto qkv_epi = [&](int ntg, const f32x4 (&acc)[2]) {
            const float bias = qkv_b[ntg * 16 + l15];
            const int m3 = ntg >> 4;              // 0=Q 1=K 2=V
            const int c = (ntg & 15) * 16 + l15;
            if (m3 == 2) {
                #pragma unroll
                for (int m = 0; m < 2; ++m)
                    #pragma unroll
                    for (int r = 0; r < 4; ++r) {
                        int t = (mg * 2 + m) * 16 + sub * 4 + r;
                        *(unsigned short*)(smem + frOffT(OFF_V, c, t)) = f2bf(acc[m][r] + bias);
                    }
            } else if (m3 == 1) {
                #pragma unroll
                for (int m = 0; m < 2; ++m)
                    #pragma unroll
                    for (int r = 0; r < 4; ++r) {
                        int t = (mg * 2 + m) * 16 + sub * 4 + r;
                        *(unsigned short*)(smem + frOff(OFF_K, t, c)) = f2bf(acc[m][r] + bias);
                    }
            } else {
                #pragma unroll
                for (int m = 0; m < 2; ++m)
                    #pragma unroll
                    for (int r = 0; r < 4; ++r) {
                        int t = (mg * 2 + m) * 16 + sub * 4 + r;
                        *(unsigned short*)(smem + frOff(OFF_Q, t, c)) = f2bf((acc[m][r] + bias) * 0.125f);
                    }
            }
        };

        bf16x8 bA[8], bB[8];
        #pragma unroll
        for (int kt = 0; kt < 8; ++kt)
            bA[kt] = *(const bf16x8*)(ws + (size_t)(((ng6 * 8) * 8 + kt) << 10) + lane * 16);

        for (int i = 0; i < 8; i += 2) {
            const int n0 = ng6 * 8 + i;
            #pragma unroll
            for (int kt = 0; kt < 8; ++kt)
                bB[kt] = *(const bf16x8*)(ws + (size_t)(((n0 + 1) * 8 + kt) << 10) + lane * 16);
            {
                f32x4 acc[2] = {z4, z4};
                #pragma unroll
                for (int kt = 0; kt < 8; ++kt)
                    #pragma unroll
                    for (int m = 0; m < 2; ++m)
                        acc[m] = mfma16(aF[m][kt], bA[kt], acc[m]);
                qkv_epi(n0, acc);
            }
            if (i + 2 < 8) {
                #pragma unroll
                for (int kt = 0; kt < 8; ++kt)
                    bA[kt] = *(const bf16x8*)(ws + (size_t)(((n0 + 2) * 8 + kt) << 10) + lane * 16);
            }
            {
                f32x4 acc[2] = {z4, z4};
                #pragma unroll
                for (int kt = 0; kt < 8; ++kt)
                    #pragma unroll
                    for (int m = 0; m < 2; ++m)
                        acc[m] = mfma16(aF[m][kt], bB[kt], acc[m]);
                qkv_epi(n0 + 1, acc);
            }
        }
    }
    __syncthreads();   // 4

    // ---- P4: attention; waves 0..7 = (head h = wid>>1, m-half ah = wid&1); waves 8-11 idle ----
    {
        const int h  = wid >> 1;
        const int ah = wid & 1;
        f32x4 sc[2][4];
        #pragma unroll
        for (int m = 0; m < 2; ++m)
            #pragma unroll
            for (int nt = 0; nt < 4; ++nt) sc[m][nt] = z4;

        if (wid < 8) {
            bf16x8 qf[2][2], kf[4][2];
            #pragma unroll
            for (int m = 0; m < 2; ++m)
                #pragma unroll
                for (int k2 = 0; k2 < 2; ++k2)
                    qf[m][k2] = *(const bf16x8*)(smem + OFF_Q + (((ah * 2 + m) * 8 + h * 2 + k2) << 10) + lane * 16);
            #pragma unroll
            for (int nt = 0; nt < 4; ++nt)
                #pragma unroll
                for (int k2 = 0; k2 < 2; ++k2)
                    kf[nt][k2] = *(const bf16x8*)(smem + OFF_K + ((nt * 8 + h * 2 + k2) << 10) + lane * 16);
            #pragma unroll
            for (int k2 = 0; k2 < 2; ++k2)
                #pragma unroll
                for (int m = 0; m < 2; ++m)
                    #pragma unroll
                    for (int nt = 0; nt < 4; ++nt)
                        sc[m][nt] = mfma16(qf[m][k2], kf[nt][k2], sc[m][nt]);
        }
        __syncthreads();   // 4a: all Q/K reads drained (OF may now overwrite K region)

        if (wid < 8) {
            const int pbase = OFF_P + h * PSZ;
            #pragma unroll
            for (int m = 0; m < 2; ++m) {
                #pragma unroll
                for (int r = 0; r < 4; ++r) {
                    const int t = (ah * 2 + m) * 16 + sub * 4 + r;
                    float v0 = sc[m][0][r];
                    float v1 = sc[m][1][r];
                    float v2 = sc[m][2][r];
                    float v3 = (l15 == 0) ? sc[m][3][r] : -1e30f;
                    float mx = fmaxf(fmaxf(v0, v1), fmaxf(v2, v3));
                    mx = fmaxf(mx, __shfl_xor(mx, 1));
                    mx = fmaxf(mx, __shfl_xor(mx, 2));
                    mx = fmaxf(mx, __shfl_xor(mx, 4));
                    mx = fmaxf(mx, __shfl_xor(mx, 8));
                    float e0 = __expf(v0 - mx), e1 = __expf(v1 - mx);
                    float e2 = __expf(v2 - mx), e3 = __expf(v3 - mx);
                    float s = e0 + e1 + e2 + e3;
                    s += __shfl_xor(s, 1);
                    s += __shfl_xor(s, 2);
                    s += __shfl_xor(s, 4);
                    s += __shfl_xor(s, 8);
                    float inv = 1.f / s;
                    if (t < TOK) {
                        unsigned short* pr = (unsigned short*)(smem + pbase + t * 144);
                        pr[l15]      = f2bf(e0 * inv);
                        pr[16 + l15] = f2bf(e1 * inv);
                        pr[32 + l15] = f2bf(e2 * inv);
                        pr[48 + l15] = f2bf(e3 * inv);
                    }
                }
            }

            // PV: O_h rows of this m-half
            bf16x8 pf[2][2], vf[4][2];
            #pragma unroll
            for (int m = 0; m < 2; ++m)
                #pragma unroll
                for (int k2 = 0; k2 < 2; ++k2) {
                    int row = (ah * 2 + m) * 16 + l15; row = row > 48 ? 48 : row;
                    pf[m][k2] = *(const bf16x8*)(smem + pbase + row * 144 + ((k2 * 32 + sub * 8) << 1));
                }
            #pragma unroll
            for (int nt = 0; nt < 4; ++nt)
                #pragma unroll
                for (int k2 = 0; k2 < 2; ++k2)
                    vf[nt][k2] = *(const bf16x8*)(smem + OFF_V + ((((h * 4 + nt) << 1) + k2) << 10) + lane * 16);

            f32x4 oc[2][4];
            #pragma unroll
            for (int m = 0; m < 2; ++m)
                #pragma unroll
                for (int nt = 0; nt < 4; ++nt) oc[m][nt] = z4;
            #pragma unroll
            for (int k2 = 0; k2 < 2; ++k2)
                #pragma unroll
                for (int m = 0; m < 2; ++m)
                    #pragma unroll
                    for (int nt = 0; nt < 4; ++nt)
                        oc[m][nt] = mfma16(pf[m][k2], vf[nt][k2], oc[m][nt]);
            #pragma unroll
            for (int m = 0; m < 2; ++m)
                #pragma unroll
                for (int nt = 0; nt < 4; ++nt)
                    #pragma unroll
                    for (int r = 0; r < 4; ++r) {
                        int t = (ah * 2 + m) * 16 + sub * 4 + r;
                        int c = h * 64 + nt * 16 + l15;
                        *(unsigned short*)(smem + frOff(OFF_OF, t, c)) = f2bf(oc[m][nt][r]);
                    }
        }
    }
    __syncthreads();   // 5

    // ---- P5: restage x -> sW (over V region; V fully consumed) ----
    float* sW = sX;
    for (int e = tid; e < TOK * CH; e += NTHR) {
        int j = e % 7; int rem = e / 7; int i = rem % 7; int c = rem / 7;
        sW[(i * 7 + j) * SX_ST + c] = x[xbase + ((size_t)c * IMG + row0 + i) * IMG + col0 + j];
    }
    __syncthreads();   // 6

    // ---- P6: proj + residual -> sW; wave (mg,ng6): ntg = ng6, ng6+6, ng6+12 (<16) ----
    {
        bf16x8 aF[2][8];
        #pragma unroll
        for (int m = 0; m < 2; ++m)
            #pragma unroll
            for (int kt = 0; kt < 8; ++kt)
                aF[m][kt] = *(const bf16x8*)(smem + OFF_OF + (((mg * 2 + m) * 8 + kt) << 10) + lane * 16);

        #pragma unroll
        for (int i = 0; i < 3; ++i) {
            const int ntg = ng6 + i * 6;
            if (ntg < 16) {
                bf16x8 bF[8];
                #pragma unroll
                for (int kt = 0; kt < 8; ++kt)
                    bF[kt] = *(const bf16x8*)(ws + (size_t)(((WS_PROJ_BLK + ntg * 8 + kt)) << 10) + lane * 16);
                f32x4 acc[2] = {z4, z4};
                #pragma unroll
                for (int kt = 0; kt < 8; ++kt)
                    #pragma unroll
                    for (int m = 0; m < 2; ++m)
                        acc[m] = mfma16(aF[m][kt], bF[kt], acc[m]);
                const int c = ntg * 16 + l15;
                const float bias = proj_b[c];
                #pragma unroll
                for (int m = 0; m < 2; ++m)
                    #pragma unroll
                    for (int r = 0; r < 4; ++r) {
                        int t = (mg * 2 + m) * 16 + sub * 4 + r;
                        if (t < TOK) sW[t * SX_ST + c] += acc[m][r] + bias;
                    }
            }
        }
    }
    __syncthreads();   // 7

    // ---- P7: LN2 stats ----
    for (int t = wid; t < TOK; t += 12) {
        const float4 v = *(const float4*)&sW[t * SX_ST + lane * 4];
        float s1 = v.x + v.y + v.z + v.w;
        float s2 = v.x * v.x + v.y * v.y + v.z * v.z + v.w * v.w;
        #pragma unroll
        for (int off = 32; off > 0; off >>= 1) {
            s1 += __shfl_xor(s1, off);
            s2 += __shfl_xor(s2, off);
        }
        if (lane == 0) {
            float m = s1 * (1.f / 256.f);
            float var = s2 * (1.f / 256.f) - m * m;
            sM[t] = m; sR[t] = rsqrtf(var + 1e-5f);
        }
    }
    __syncthreads();   // 8

    // ---- P8: LN2 normalize -> n2F ----
    for (int e = tid; e < 2048; e += NTHR) {
        int t = e & 63, cb = e >> 6;
        char* dst = smem + OFF_AF + (((t >> 4) * 8 + (cb >> 2)) << 10)
                  + (((((cb & 3) << 4) | (t & 15))) << 4);
        if (t < TOK) {
            const float* xr = sW + t * SX_ST + cb * 8;
            float4 xa = *(const float4*)xr;
            float4 xb = *(const float4*)(xr + 4);
            float m = sM[t], rs = sR[t];
            int c = cb * 8;
            u16x8 o;
            o[0] = f2bf((xa.x - m) * rs * sG2[c + 0] + sB2[c + 0]);
            o[1] = f2bf((xa.y - m) * rs * sG2[c + 1] + sB2[c + 1]);
            o[2] = f2bf((xa.z - m) * rs * sG2[c + 2] + sB2[c + 2]);
            o[3] = f2bf((xa.w - m) * rs * sG2[c + 3] + sB2[c + 3]);
            o[4] = f2bf((xb.x - m) * rs * sG2[c + 4] + sB2[c + 4]);
            o[5] = f2bf((xb.y - m) * rs * sG2[c + 5] + sB2[c + 5]);
            o[6] = f2bf((xb.z - m) * rs * sG2[c + 6] + sB2[c + 6]);
            o[7] = f2bf((xb.w - m) * rs * sG2[c + 7] + sB2[c + 7]);
            *(u16x8*)dst = o;
        } else {
            u16x8 z = {0, 0, 0, 0, 0, 0, 0, 0};
            *(u16x8*)dst = z;
        }
    }
    __syncthreads();   // 9

    // ---- P9: MLP in two K-halves; hmid ping-pongs in HM ----
    {
        f32x4 acc2[3][2];
        #pragma unroll
        for (int i = 0; i < 3; ++i) { acc2[i][0] = z4; acc2[i][1] = z4; }

        for (int half = 0; half < 2; ++half) {
            // MLP1: n2 @ w1[:, half*256 +: 256] + b1, GELU -> HM; ntg = ng6 + 6i (<16)
            {
                bf16x8 nf[2][8];
                #pragma unroll
                for (int m = 0; m < 2; ++m)
                    #pragma unroll
                    for (int kt = 0; kt < 8; ++kt)
                        nf[m][kt] = *(const bf16x8*)(smem + OFF_AF + (((mg * 2 + m) * 8 + kt) << 10) + lane * 16);

                #pragma unroll
                for (int i = 0; i < 3; ++i) {
                    const int ntg = ng6 + i * 6;
                    if (ntg < 16) {
                        bf16x8 bF[8];
                        #pragma unroll
                        for (int kt = 0; kt < 8; ++kt)
                            bF[kt] = *(const bf16x8*)(ws + (size_t)(((WS_W1_BLK + (half * 16 + ntg) * 8 + kt)) << 10) + lane * 16);
                        f32x4 acc[2] = {z4, z4};
                        #pragma unroll
                        for (int kt = 0; kt < 8; ++kt)
                            #pragma unroll
                            for (int m = 0; m < 2; ++m)
                                acc[m] = mfma16(nf[m][kt], bF[kt], acc[m]);
                        const int chm = ntg * 16 + l15;
                        const float bias = b1[half * 256 + chm];
                        #pragma unroll
                        for (int m = 0; m < 2; ++m)
                            #pragma unroll
                            for (int r = 0; r < 4; ++r) {
                                int t = (mg * 2 + m) * 16 + sub * 4 + r;
                                if (t < TOK) {
                                    float v = acc[m][r] + bias;
                                    float u = v * (1.5957691216f + 0.07135481627f * v * v);
                                    float g = v / (1.f + __expf(-u));
                                    *(unsigned short*)(smem + frOff(OFF_HM, t, chm)) = f2bf(g);
                                }
                            }
                    }
                }
            }
            __syncthreads();   // HM ready

            // MLP2 partial: acc2 += HM @ w2[half*256 +: 256, :]; ntg = ng6 + 6i (<16)
            {
                bf16x8 hf[2][8];
                #pragma unroll
                for (int m = 0; m < 2; ++m)
                    #pragma unroll
                    for (int kt = 0; kt < 8; ++kt)
                        hf[m][kt] = *(const bf16x8*)(smem + OFF_HM + (((mg * 2 + m) * 8 + kt) << 10) + lane * 16);

                #pragma unroll
                for (int i = 0; i < 3; ++i) {
                    const int ntg = ng6 + i * 6;
                    if (ntg < 16) {
                        bf16x8 bF[8];
                        #pragma unroll
                        for (int kt = 0; kt < 8; ++kt)
                            bF[kt] = *(const bf16x8*)(ws + (size_t)(((WS_W2_BLK + ntg * 16 + half * 8 + kt)) << 10) + lane * 16);
                        #pragma unroll
                        for (int kt = 0; kt < 8; ++kt)
                            #pragma unroll
                            for (int m = 0; m < 2; ++m)
                                acc2[i][m] = mfma16(hf[m][kt], bF[kt], acc2[i][m]);
                    }
                }
            }
            __syncthreads();   // HM reads done
        }

        // epilogue: win2 += mlp2 + b2
        #pragma unroll
        for (int i = 0; i < 3; ++i) {
            const int ntg = ng6 + i * 6;
            if (ntg < 16) {
                const int c = ntg * 16 + l15;
                const float bias = b2[c];
                #pragma unroll
                for (int m = 0; m < 2; ++m)
                    #pragma unroll
                    for (int r = 0; r < 4; ++r) {
                        int t = (mg * 2 + m) * 16 + sub * 4 + r;
                        if (t < TOK) sW[t * SX_ST + c] += acc2[i][m][r] + bias;
                    }
            }
        }
    }
    __syncthreads();   // final

    // ---- P10: window-reverse store ----
    for (int e = tid; e < TOK * CH; e += NTHR) {
        int j = e % 7; int rem = e / 7; int i = rem % 7; int c = rem / 7;
        y[xbase + ((size_t)c * IMG + row0 + i) * IMG + col0 + j] = sW[(i * 7 + j) * SX_ST + c];
    }
}

extern "C" void kernel_launch(void* const* d_in, const int* in_sizes, int n_in,
                              void* d_out, int out_size, void* d_ws, size_t ws_size,
                              hipStream_t stream) {
    const float* x      = (const float*)d_in[0];
    const float* ln1_g  = (const float*)d_in[1];
    const float* ln1_b  = (const float*)d_in[2];
    const float* qkv_w  = (const float*)d_in[3];
    const float* qkv_b  = (const float*)d_in[4];
    const float* proj_w = (const float*)d_in[5];
    const float* proj_b = (const float*)d_in[6];
    const float* ln2_g  = (const float*)d_in[7];
    const float* ln2_b  = (const float*)d_in[8];
    const float* w1     = (const float*)d_in[9];
    const float* b1     = (const float*)d_in[10];
    const float* w2     = (const float*)d_in[11];
    const float* b2     = (const float*)d_in[12];

    hipLaunchKernelGGL(prepack, dim3(1024), dim3(64), 0, stream,
                       qkv_w, proj_w, w1, w2, (char*)d_ws);
    hipLaunchKernelGGL(swin_block, dim3(NWIN), dim3(NTHR), 0, stream,
                       x, ln1_g, ln1_b, qkv_b, proj_b, ln2_g, ln2_b, b1, b2,
                       (const char*)d_ws, (float*)d_out);
}

// Round 9
// 865.005 us; speedup vs baseline: 1.9182x; 1.1703x over previous
//
#include <hip/hip_runtime.h>
#include <hip/hip_bf16.h>

typedef __bf16 bf16x8 __attribute__((ext_vector_type(8)));
typedef float  f32x4  __attribute__((ext_vector_type(4)));
typedef unsigned short u16x8 __attribute__((ext_vector_type(8)));

#define CH    256
#define IMG   112
#define WSZ   7
#define TOK   49
#define NWIN  4096
#define HID   512
#define NTHR  512

#define SX_ST 260          // f32 row stride for sX / sW staging

// ---- LDS arena (byte offsets), time-multiplexed ----
#define OFF_V    0
#define OFF_AF   51200
#define OFF_P    51200
#define PSZ      7168
#define OFF_Q    83968
#define OFF_HM   83968
#define OFF_K    116736
#define OFF_OF   116736
#define OFF_MR   149504     // sM[64], sR[64]
#define OFF_PRM  150016     // sG1,sB1,sG2,sB2 (each 256 f32)
#define SMEM_SZ  154112

// ---- d_ws layout: bf16 B-fragment blocks, 1KB each ----
#define WS_PROJ_BLK 384
#define WS_W1_BLK   512
#define WS_W2_BLK   768

__device__ __forceinline__ unsigned short f2bf(float f) {
    __bf16 h = (__bf16)f;
    return __builtin_bit_cast(unsigned short, h);
}

__device__ __forceinline__ f32x4 mfma16(bf16x8 a, bf16x8 b, f32x4 c) {
    return __builtin_amdgcn_mfma_f32_16x16x32_bf16(a, b, c, 0, 0, 0);
}

__device__ __forceinline__ int frOff(int base, int t, int c) {
    return base + (((t >> 4) * 8 + (c >> 5)) << 10)
                + (((((c >> 3) & 3) << 4) | (t & 15)) << 4)
                + ((c & 7) << 1);
}
__device__ __forceinline__ int frOffT(int base, int c, int t) {
    return base + ((((c >> 4) << 1) + (t >> 5)) << 10)
                + (((((t >> 3) & 3) << 4) | (c & 15)) << 4)
                + ((t & 7) << 1);
}

// ---------------- prepack: fp32 weights -> bf16 B-fragment blocks in d_ws ----------------
extern "C" __global__ __launch_bounds__(64)
void prepack(const float* __restrict__ qkv_w, const float* __restrict__ proj_w,
             const float* __restrict__ w1, const float* __restrict__ w2,
             char* __restrict__ ws)
{
    const int blk = blockIdx.x, l = threadIdx.x;
    const float* W; int nt, kt, ncols;
    if (blk < WS_PROJ_BLK)      { W = qkv_w;  int i = blk;               nt = i >> 3; kt = i & 7;  ncols = 768; }
    else if (blk < WS_W1_BLK)   { W = proj_w; int i = blk - WS_PROJ_BLK; nt = i >> 3; kt = i & 7;  ncols = 256; }
    else if (blk < WS_W2_BLK)   { W = w1;     int i = blk - WS_W1_BLK;   nt = i >> 3; kt = i & 7;  ncols = 512; }
    else                        { W = w2;     int i = blk - WS_W2_BLK;   nt = i >> 4; kt = i & 15; ncols = 256; }
    const int n  = nt * 16 + (l & 15);
    const int k0 = kt * 32 + (l >> 4) * 8;
    u16x8 o;
    #pragma unroll
    for (int j = 0; j < 8; ++j) o[j] = f2bf(W[(size_t)(k0 + j) * ncols + n]);
    *(u16x8*)(ws + (size_t)blk * 1024 + l * 16) = o;
}

// ---------------- main fused block: 8 waves, N-only GEMM split ----------------
extern "C" __global__ __launch_bounds__(NTHR, 1)
void swin_block(const float* __restrict__ x,
                const float* __restrict__ ln1_g, const float* __restrict__ ln1_b,
                const float* __restrict__ qkv_b,
                const float* __restrict__ proj_b,
                const float* __restrict__ ln2_g, const float* __restrict__ ln2_b,
                const float* __restrict__ b1, const float* __restrict__ b2,
                const char* __restrict__ ws,
                float* __restrict__ y)
{
    __shared__ __align__(16) char smem[SMEM_SZ];
    float* sX = (float*)(smem + 0);          // also sW later
    float* sM = (float*)(smem + OFF_MR);
    float* sR = sM + 64;
    float* sG1 = (float*)(smem + OFF_PRM);
    float* sB1 = sG1 + 256;
    float* sG2 = sB1 + 256;
    float* sB2 = sG2 + 256;

    const int tid  = threadIdx.x;
    const int wid  = tid >> 6;       // 0..7
    const int lane = tid & 63;
    const int sub  = lane >> 4;
    const int l15  = lane & 15;
    const int li7  = lane / 7;       // spatial row (lane<49), computed ONCE
    const int lj7  = lane - li7 * 7; // spatial col

    const int n  = blockIdx.x;
    const int b  = n >> 8;
    const int wh = (n >> 4) & 15;
    const int ww = n & 15;
    const int row0 = wh * WSZ, col0 = ww * WSZ;
    const size_t xbase = (size_t)b * CH * IMG * IMG;

    const f32x4 z4 = {0.f, 0.f, 0.f, 0.f};

    // ---- P0: stage x -> sX (lane = spatial token, loop over channels) ----
    if (lane < TOK) {
        const float* xs = x + xbase + (size_t)(row0 + li7) * IMG + (col0 + lj7);
        float* dst = sX + lane * SX_ST;
        for (int c = wid; c < CH; c += 8)
            dst[c] = xs[(size_t)c * (IMG * IMG)];
    }
    if (tid < 512) {
        int t2 = tid & 255;
        if (tid < 256) { sG1[t2] = ln1_g[t2]; sB1[t2] = ln1_b[t2]; }
        else           { sG2[t2] = ln2_g[t2]; sB2[t2] = ln2_b[t2]; }
    }
    __syncthreads();   // 1

    // ---- P1: LN1 stats ----
    for (int t = wid; t < TOK; t += 8) {
        const float4 v = *(const float4*)&sX[t * SX_ST + lane * 4];
        float s1 = v.x + v.y + v.z + v.w;
        float s2 = v.x * v.x + v.y * v.y + v.z * v.z + v.w * v.w;
        #pragma unroll
        for (int off = 32; off > 0; off >>= 1) {
            s1 += __shfl_xor(s1, off);
            s2 += __shfl_xor(s2, off);
        }
        if (lane == 0) {
            float m = s1 * (1.f / 256.f);
            float var = s2 * (1.f / 256.f) - m * m;
            sM[t] = m; sR[t] = rsqrtf(var + 1e-5f);
        }
    }
    __syncthreads();   // 2

    // ---- P2: normalize -> n1F fragment blocks; zero pad rows ----
    for (int e = tid; e < 2048; e += NTHR) {
        int t = e & 63, cb = e >> 6;
        char* dst = smem + OFF_AF + (((t >> 4) * 8 + (cb >> 2)) << 10)
                  + (((((cb & 3) << 4) | (t & 15))) << 4);
        if (t < TOK) {
            const float* xr = sX + t * SX_ST + cb * 8;
            float4 xa = *(const float4*)xr;
            float4 xb = *(const float4*)(xr + 4);
            float m = sM[t], rs = sR[t];
            int c = cb * 8;
            u16x8 o;
            o[0] = f2bf((xa.x - m) * rs * sG1[c + 0] + sB1[c + 0]);
            o[1] = f2bf((xa.y - m) * rs * sG1[c + 1] + sB1[c + 1]);
            o[2] = f2bf((xa.z - m) * rs * sG1[c + 2] + sB1[c + 2]);
            o[3] = f2bf((xa.w - m) * rs * sG1[c + 3] + sB1[c + 3]);
            o[4] = f2bf((xb.x - m) * rs * sG1[c + 4] + sB1[c + 4]);
            o[5] = f2bf((xb.y - m) * rs * sG1[c + 5] + sB1[c + 5]);
            o[6] = f2bf((xb.z - m) * rs * sG1[c + 6] + sB1[c + 6]);
            o[7] = f2bf((xb.w - m) * rs * sG1[c + 7] + sB1[c + 7]);
            *(u16x8*)dst = o;
        } else {
            u16x8 z = {0, 0, 0, 0, 0, 0, 0, 0};
            *(u16x8*)dst = z;
        }
    }
    __syncthreads();   // 3

    // ---- P3: QKV GEMM (M=64,N=768,K=256); wave owns ALL row-tiles, ntg = wid*6 + i ----
    {
        bf16x8 aF[4][8];
        #pragma unroll
        for (int mt = 0; mt < 4; ++mt)
            #pragma unroll
            for (int kt = 0; kt < 8; ++kt)
                aF[mt][kt] = *(const bf16x8*)(smem + OFF_AF + ((mt * 8 + kt) << 10) + lane * 16);

        auto qkv_epi = [&](int ntg, const f32x4 (&acc)[4]) {
            const float bias = qkv_b[ntg * 16 + l15];
            const int m3 = ntg >> 4;              // 0=Q 1=K 2=V
            const int c = (ntg & 15) * 16 + l15;
            if (m3 == 2) {
                #pragma unroll
                for (int mt = 0; mt < 4; ++mt)
                    #pragma unroll
                    for (int r = 0; r < 4; ++r) {
                        int t = mt * 16 + sub * 4 + r;
                        *(unsigned short*)(smem + frOffT(OFF_V, c, t)) = f2bf(acc[mt][r] + bias);
                    }
            } else if (m3 == 1) {
                #pragma unroll
                for (int mt = 0; mt < 4; ++mt)
                    #pragma unroll
                    for (int r = 0; r < 4; ++r) {
                        int t = mt * 16 + sub * 4 + r;
                        *(unsigned short*)(smem + frOff(OFF_K, t, c)) = f2bf(acc[mt][r] + bias);
                    }
            } else {
                #pragma unroll
                for (int mt = 0; mt < 4; ++mt)
                    #pragma unroll
                    for (int r = 0; r < 4; ++r) {
                        int t = mt * 16 + sub * 4 + r;
                        *(unsigned short*)(smem + frOff(OFF_Q, t, c)) = f2bf((acc[mt][r] + bias) * 0.125f);
                    }
            }
        };

        bf16x8 bA[8], bB[8];
        #pragma unroll
        for (int kt = 0; kt < 8; ++kt)
            bA[kt] = *(const bf16x8*)(ws + (size_t)(((wid * 6) * 8 + kt) << 10) + lane * 16);

        for (int i = 0; i < 6; i += 2) {
            const int n0 = wid * 6 + i;
            #pragma unroll
            for (int kt = 0; kt < 8; ++kt)
                bB[kt] = *(const bf16x8*)(ws + (size_t)(((n0 + 1) * 8 + kt) << 10) + lane * 16);
            {
                f32x4 acc[4] = {z4, z4, z4, z4};
                #pragma unroll
                for (int kt = 0; kt < 8; ++kt)
                    #pragma unroll
                    for (int mt = 0; mt < 4; ++mt)
                        acc[mt] = mfma16(aF[mt][kt], bA[kt], acc[mt]);
                qkv_epi(n0, acc);
            }
            if (i + 2 < 6) {
                #pragma unroll
                for (int kt = 0; kt < 8; ++kt)
                    bA[kt] = *(const bf16x8*)(ws + (size_t)(((n0 + 2) * 8 + kt) << 10) + lane * 16);
            }
            {
                f32x4 acc[4] = {z4, z4, z4, z4};
                #pragma unroll
                for (int kt = 0; kt < 8; ++kt)
                    #pragma unroll
                    for (int mt = 0; mt < 4; ++mt)
                        acc[mt] = mfma16(aF[mt][kt], bB[kt], acc[mt]);
                qkv_epi(n0 + 1, acc);
            }
        }
    }
    __syncthreads();   // 4

    // ---- P4: attention; wave = (head h = wid>>1, m-half ah = wid&1) ----
    {
        const int h  = wid >> 1;
        const int ah = wid & 1;
        f32x4 sc[2][4];
        #pragma unroll
        for (int m = 0; m < 2; ++m)
            #pragma unroll
            for (int nt = 0; nt < 4; ++nt) sc[m][nt] = z4;

        {
            bf16x8 qf[2][2], kf[4][2];
            #pragma unroll
            for (int m = 0; m < 2; ++m)
                #pragma unroll
                for (int k2 = 0; k2 < 2; ++k2)
                    qf[m][k2] = *(const bf16x8*)(smem + OFF_Q + (((ah * 2 + m) * 8 + h * 2 + k2) << 10) + lane * 16);
            #pragma unroll
            for (int nt = 0; nt < 4; ++nt)
                #pragma unroll
                for (int k2 = 0; k2 < 2; ++k2)
                    kf[nt][k2] = *(const bf16x8*)(smem + OFF_K + ((nt * 8 + h * 2 + k2) << 10) + lane * 16);
            #pragma unroll
            for (int k2 = 0; k2 < 2; ++k2)
                #pragma unroll
                for (int m = 0; m < 2; ++m)
                    #pragma unroll
                    for (int nt = 0; nt < 4; ++nt)
                        sc[m][nt] = mfma16(qf[m][k2], kf[nt][k2], sc[m][nt]);
        }
        __syncthreads();   // 4a: Q/K reads drained (OF may overwrite K region)

        const int pbase = OFF_P + h * PSZ;
        #pragma unroll
        for (int m = 0; m < 2; ++m) {
            #pragma unroll
            for (int r = 0; r < 4; ++r) {
                const int t = (ah * 2 + m) * 16 + sub * 4 + r;
                float v0 = sc[m][0][r];
                float v1 = sc[m][1][r];
                float v2 = sc[m][2][r];
                float v3 = (l15 == 0) ? sc[m][3][r] : -1e30f;
                float mx = fmaxf(fmaxf(v0, v1), fmaxf(v2, v3));
                mx = fmaxf(mx, __shfl_xor(mx, 1));
                mx = fmaxf(mx, __shfl_xor(mx, 2));
                mx = fmaxf(mx, __shfl_xor(mx, 4));
                mx = fmaxf(mx, __shfl_xor(mx, 8));
                float e0 = __expf(v0 - mx), e1 = __expf(v1 - mx);
                float e2 = __expf(v2 - mx), e3 = __expf(v3 - mx);
                float s = e0 + e1 + e2 + e3;
                s += __shfl_xor(s, 1);
                s += __shfl_xor(s, 2);
                s += __shfl_xor(s, 4);
                s += __shfl_xor(s, 8);
                float inv = 1.f / s;
                if (t < TOK) {
                    unsigned short* pr = (unsigned short*)(smem + pbase + t * 144);
                    pr[l15]      = f2bf(e0 * inv);
                    pr[16 + l15] = f2bf(e1 * inv);
                    pr[32 + l15] = f2bf(e2 * inv);
                    pr[48 + l15] = f2bf(e3 * inv);
                }
            }
        }

        // PV: O_h rows of this m-half (P rows wave-local)
        bf16x8 pf[2][2], vf[4][2];
        #pragma unroll
        for (int m = 0; m < 2; ++m)
            #pragma unroll
            for (int k2 = 0; k2 < 2; ++k2) {
                int row = (ah * 2 + m) * 16 + l15; row = row > 48 ? 48 : row;
                pf[m][k2] = *(const bf16x8*)(smem + pbase + row * 144 + ((k2 * 32 + sub * 8) << 1));
            }
        #pragma unroll
        for (int nt = 0; nt < 4; ++nt)
            #pragma unroll
            for (int k2 = 0; k2 < 2; ++k2)
                vf[nt][k2] = *(const bf16x8*)(smem + OFF_V + ((((h * 4 + nt) << 1) + k2) << 10) + lane * 16);

        f32x4 oc[2][4];
        #pragma unroll
        for (int m = 0; m < 2; ++m)
            #pragma unroll
            for (int nt = 0; nt < 4; ++nt) oc[m][nt] = z4;
        #pragma unroll
        for (int k2 = 0; k2 < 2; ++k2)
            #pragma unroll
            for (int m = 0; m < 2; ++m)
                #pragma unroll
                for (int nt = 0; nt < 4; ++nt)
                    oc[m][nt] = mfma16(pf[m][k2], vf[nt][k2], oc[m][nt]);
        #pragma unroll
        for (int m = 0; m < 2; ++m)
            #pragma unroll
            for (int nt = 0; nt < 4; ++nt)
                #pragma unroll
                for (int r = 0; r < 4; ++r) {
                    int t = (ah * 2 + m) * 16 + sub * 4 + r;
                    int c = h * 64 + nt * 16 + l15;
                    *(unsigned short*)(smem + frOff(OFF_OF, t, c)) = f2bf(oc[m][nt][r]);
                }
    }
    __syncthreads();   // 5

    // ---- P5: restage x -> sW (V region consumed) ----
    float* sW = sX;
    if (lane < TOK) {
        const float* xs = x + xbase + (size_t)(row0 + li7) * IMG + (col0 + lj7);
        float* dst = sW + lane * SX_ST;
        for (int c = wid; c < CH; c += 8)
            dst[c] = xs[(size_t)c * (IMG * IMG)];
    }
    __syncthreads();   // 6

    // ---- P6: proj + residual -> sW; wave owns all row-tiles, ntg = wid*2 + i ----
    {
        bf16x8 aF[4][8];
        #pragma unroll
        for (int mt = 0; mt < 4; ++mt)
            #pragma unroll
            for (int kt = 0; kt < 8; ++kt)
                aF[mt][kt] = *(const bf16x8*)(smem + OFF_OF + ((mt * 8 + kt) << 10) + lane * 16);

        #pragma unroll
        for (int i = 0; i < 2; ++i) {
            const int ntg = wid * 2 + i;
            bf16x8 bF[8];
            #pragma unroll
            for (int kt = 0; kt < 8; ++kt)
                bF[kt] = *(const bf16x8*)(ws + (size_t)(((WS_PROJ_BLK + ntg * 8 + kt)) << 10) + lane * 16);
            f32x4 acc[4] = {z4, z4, z4, z4};
            #pragma unroll
            for (int kt = 0; kt < 8; ++kt)
                #pragma unroll
                for (int mt = 0; mt < 4; ++mt)
                    acc[mt] = mfma16(aF[mt][kt], bF[kt], acc[mt]);
            const int c = ntg * 16 + l15;
            const float bias = proj_b[c];
            #pragma unroll
            for (int mt = 0; mt < 4; ++mt)
                #pragma unroll
                for (int r = 0; r < 4; ++r) {
                    int t = mt * 16 + sub * 4 + r;
                    if (t < TOK) sW[t * SX_ST + c] += acc[mt][r] + bias;
                }
        }
    }
    __syncthreads();   // 7

    // ---- P7: LN2 stats ----
    for (int t = wid; t < TOK; t += 8) {
        const float4 v = *(const float4*)&sW[t * SX_ST + lane * 4];
        float s1 = v.x + v.y + v.z + v.w;
        float s2 = v.x * v.x + v.y * v.y + v.z * v.z + v.w * v.w;
        #pragma unroll
        for (int off = 32; off > 0; off >>= 1) {
            s1 += __shfl_xor(s1, off);
            s2 += __shfl_xor(s2, off);
        }
        if (lane == 0) {
            float m = s1 * (1.f / 256.f);
            float var = s2 * (1.f / 256.f) - m * m;
            sM[t] = m; sR[t] = rsqrtf(var + 1e-5f);
        }
    }
    __syncthreads();   // 8

    // ---- P8: LN2 normalize -> n2F ----
    for (int e = tid; e < 2048; e += NTHR) {
        int t = e & 63, cb = e >> 6;
        char* dst = smem + OFF_AF + (((t >> 4) * 8 + (cb >> 2)) << 10)
                  + (((((cb & 3) << 4) | (t & 15))) << 4);
        if (t < TOK) {
            const float* xr = sW + t * SX_ST + cb * 8;
            float4 xa = *(const float4*)xr;
            float4 xb = *(const float4*)(xr + 4);
            float m = sM[t], rs = sR[t];
            int c = cb * 8;
            u16x8 o;
            o[0] = f2bf((xa.x - m) * rs * sG2[c + 0] + sB2[c + 0]);
            o[1] = f2bf((xa.y - m) * rs * sG2[c + 1] + sB2[c + 1]);
            o[2] = f2bf((xa.z - m) * rs * sG2[c + 2] + sB2[c + 2]);
            o[3] = f2bf((xa.w - m) * rs * sG2[c + 3] + sB2[c + 3]);
            o[4] = f2bf((xb.x - m) * rs * sG2[c + 4] + sB2[c + 4]);
            o[5] = f2bf((xb.y - m) * rs * sG2[c + 5] + sB2[c + 5]);
            o[6] = f2bf((xb.z - m) * rs * sG2[c + 6] + sB2[c + 6]);
            o[7] = f2bf((xb.w - m) * rs * sG2[c + 7] + sB2[c + 7]);
            *(u16x8*)dst = o;
        } else {
            u16x8 z = {0, 0, 0, 0, 0, 0, 0, 0};
            *(u16x8*)dst = z;
        }
    }
    __syncthreads();   // 9

    // ---- P9: MLP in two K-halves; hmid ping-pongs in HM ----
    {
        f32x4 acc2[2][4];
        #pragma unroll
        for (int i = 0; i < 2; ++i)
            #pragma unroll
            for (int mt = 0; mt < 4; ++mt) acc2[i][mt] = z4;

        for (int half = 0; half < 2; ++half) {
            // MLP1: n2 @ w1[:, half*256 +: 256] + b1, GELU -> HM; ntg = wid*2 + i
            {
                bf16x8 nf[4][8];
                #pragma unroll
                for (int mt = 0; mt < 4; ++mt)
                    #pragma unroll
                    for (int kt = 0; kt < 8; ++kt)
                        nf[mt][kt] = *(const bf16x8*)(smem + OFF_AF + ((mt * 8 + kt) << 10) + lane * 16);

                #pragma unroll
                for (int i = 0; i < 2; ++i) {
                    const int ntg = wid * 2 + i;
                    bf16x8 bF[8];
                    #pragma unroll
                    for (int kt = 0; kt < 8; ++kt)
                        bF[kt] = *(const bf16x8*)(ws + (size_t)(((WS_W1_BLK + (half * 16 + ntg) * 8 + kt)) << 10) + lane * 16);
                    f32x4 acc[4] = {z4, z4, z4, z4};
                    #pragma unroll
                    for (int kt = 0; kt < 8; ++kt)
                        #pragma unroll
                        for (int mt = 0; mt < 4; ++mt)
                            acc[mt] = mfma16(nf[mt][kt], bF[kt], acc[mt]);
                    const int chm = ntg * 16 + l15;
                    const float bias = b1[half * 256 + chm];
                    #pragma unroll
                    for (int mt = 0; mt < 4; ++mt)
                        #pragma unroll
                        for (int r = 0; r < 4; ++r) {
                            int t = mt * 16 + sub * 4 + r;
                            if (t < TOK) {
                                float v = acc[mt][r] + bias;
                                float u = v * (1.5957691216f + 0.07135481627f * v * v);
                                float g = v / (1.f + __expf(-u));
                                *(unsigned short*)(smem + frOff(OFF_HM, t, chm)) = f2bf(g);
                            }
                        }
                }
            }
            __syncthreads();   // HM ready

            // MLP2 partial: acc2 += HM @ w2[half*256 +: 256, :]; ntg = wid*2 + i
            {
                bf16x8 hf[4][8];
                #pragma unroll
                for (int mt = 0; mt < 4; ++mt)
                    #pragma unroll
                    for (int kt = 0; kt < 8; ++kt)
                        hf[mt][kt] = *(const bf16x8*)(smem + OFF_HM + ((mt * 8 + kt) << 10) + lane * 16);

                #pragma unroll
                for (int i = 0; i < 2; ++i) {
                    const int ntg = wid * 2 + i;
                    bf16x8 bF[8];
                    #pragma unroll
                    for (int kt = 0; kt < 8; ++kt)
                        bF[kt] = *(const bf16x8*)(ws + (size_t)(((WS_W2_BLK + ntg * 16 + half * 8 + kt)) << 10) + lane * 16);
                    #pragma unroll
                    for (int kt = 0; kt < 8; ++kt)
                        #pragma unroll
                        for (int mt = 0; mt < 4; ++mt)
                            acc2[i][mt] = mfma16(hf[mt][kt], bF[kt], acc2[i][mt]);
                }
            }
            __syncthreads();   // HM reads done
        }

        // epilogue: win2 += mlp2 + b2
        #pragma unroll
        for (int i = 0; i < 2; ++i) {
            const int c = (wid * 2 + i) * 16 + l15;
            const float bias = b2[c];
            #pragma unroll
            for (int mt = 0; mt < 4; ++mt)
                #pragma unroll
                for (int r = 0; r < 4; ++r) {
                    int t = mt * 16 + sub * 4 + r;
                    if (t < TOK) sW[t * SX_ST + c] += acc2[i][mt][r] + bias;
                }
        }
    }
    __syncthreads();   // final

    // ---- P10: window-reverse store (lane = spatial token) ----
    if (lane < TOK) {
        float* ys = y + xbase + (size_t)(row0 + li7) * IMG + (col0 + lj7);
        const float* src = sW + lane * SX_ST;
        for (int c = wid; c < CH; c += 8)
            ys[(size_t)c * (IMG * IMG)] = src[c];
    }
}

extern "C" void kernel_launch(void* const* d_in, const int* in_sizes, int n_in,
                              void* d_out, int out_size, void* d_ws, size_t ws_size,
                              hipStream_t stream) {
    const float* x      = (const float*)d_in[0];
    const float* ln1_g  = (const float*)d_in[1];
    const float* ln1_b  = (const float*)d_in[2];
    const float* qkv_w  = (const float*)d_in[3];
    const float* qkv_b  = (const float*)d_in[4];
    const float* proj_w = (const float*)d_in[5];
    const float* proj_b = (const float*)d_in[6];
    const float* ln2_g  = (const float*)d_in[7];
    const float* ln2_b  = (const float*)d_in[8];
    const float* w1     = (const float*)d_in[9];
    const float* b1     = (const float*)d_in[10];
    const float* w2     = (const float*)d_in[11];
    const float* b2     = (const float*)d_in[12];

    hipLaunchKernelGGL(prepack, dim3(1024), dim3(64), 0, stream,
                       qkv_w, proj_w, w1, w2, (char*)d_ws);
    hipLaunchKernelGGL(swin_block, dim3(NWIN), dim3(NTHR), 0, stream,
                       x, ln1_g, ln1_b, qkv_b, proj_b, ln2_g, ln2_b, b1, b2,
                       (const char*)d_ws, (float*)d_out);
}